// Round 12
// baseline (739.578 us; speedup 1.0000x reference)
//
#include <hip/hip_runtime.h>
#include <math.h>

#define DXY   64
#define NN    4096      // 64*64
#define NB    2
#define CP    65        // LDS complex pitch (2-way conflicts free; R5 vs R7 A/B)

#define R22 0.7071067811865476f

__device__ __forceinline__ void cmul_ip(float2& a, float wr, float wi) {
    float t = a.x * wr - a.y * wi;
    a.y = a.x * wi + a.y * wr;
    a.x = t;
}

// DIF radix-2 butterfly: [a,b] -> [a+b, (a-b)*w]
__device__ __forceinline__ void bf2(float2& a, float2& b, float wr, float wi) {
    float tr = a.x - b.x, ti = a.y - b.y;
    a.x += b.x; a.y += b.y;
    b.x = tr * wr - ti * wi;
    b.y = tr * wi + ti * wr;
}
// inverse butterfly (caller passes conj tw): b'=b*w; [a,b] -> [a+b', a-b']
__device__ __forceinline__ void ibf2(float2& a, float2& b, float wr, float wi) {
    float br = b.x * wr - b.y * wi, bi = b.x * wi + b.y * wr;
    b.x = a.x - br; b.y = a.y - bi;
    a.x += br; a.y += bi;
}

// 8-pt DIF FFT, natural in -> bit-reversed out
__device__ __forceinline__ void fft8_fwd(float2* y) {
    bf2(y[0], y[4], 1.f, 0.f);  bf2(y[1], y[5],  R22, -R22);
    bf2(y[2], y[6], 0.f, -1.f); bf2(y[3], y[7], -R22, -R22);
    bf2(y[0], y[2], 1.f, 0.f);  bf2(y[1], y[3], 0.f, -1.f);
    bf2(y[4], y[6], 1.f, 0.f);  bf2(y[5], y[7], 0.f, -1.f);
    bf2(y[0], y[1], 1.f, 0.f);  bf2(y[2], y[3], 1.f, 0.f);
    bf2(y[4], y[5], 1.f, 0.f);  bf2(y[6], y[7], 1.f, 0.f);
}
// exact unscaled inverse (consumes fwd layout) = 8 * IDFT8.
// Stage order reversed; each twiddle conjugated (incl. (y3,y7): (-R22,+R22)).
__device__ __forceinline__ void fft8_inv(float2* y) {
    ibf2(y[0], y[1], 1.f, 0.f); ibf2(y[2], y[3], 1.f, 0.f);
    ibf2(y[4], y[5], 1.f, 0.f); ibf2(y[6], y[7], 1.f, 0.f);
    ibf2(y[0], y[2], 1.f, 0.f); ibf2(y[1], y[3], 0.f, 1.f);
    ibf2(y[4], y[6], 1.f, 0.f); ibf2(y[5], y[7], 0.f, 1.f);
    ibf2(y[0], y[4], 1.f, 0.f); ibf2(y[1], y[5],  R22,  R22);
    ibf2(y[2], y[6], 0.f, 1.f); ibf2(y[3], y[7], -R22,  R22);
}

// Cross radix-8 combine: returns sum_j x_j * W8^{j*k1}, parameterized by
// s2 = W8^{4k1} (=+-1), c1 = W8^{2k1}, w8 = W8^{k1}. Conj consts -> inverse.
__device__ __forceinline__ float2 cross8(
    float2 x0, float2 x1, float2 x2, float2 x3,
    float2 x4, float2 x5, float2 x6, float2 x7,
    float s2, float c1r, float c1i, float w8x, float w8y)
{
    float e0r = fmaf(s2, x4.x, x0.x), e0i = fmaf(s2, x4.y, x0.y);
    float e1r = fmaf(s2, x5.x, x1.x), e1i = fmaf(s2, x5.y, x1.y);
    float e2r = fmaf(s2, x6.x, x2.x), e2i = fmaf(s2, x6.y, x2.y);
    float e3r = fmaf(s2, x7.x, x3.x), e3i = fmaf(s2, x7.y, x3.y);
    float f0r = e0r + c1r * e2r - c1i * e2i;
    float f0i = e0i + c1r * e2i + c1i * e2r;
    float f1r = e1r + c1r * e3r - c1i * e3i;
    float f1i = e1i + c1r * e3i + c1i * e3r;
    float2 o;
    o.x = f0r + w8x * f1r - w8y * f1i;
    o.y = f0i + w8x * f1i + w8y * f1r;
    return o;
}

// Forward 64-pt over 64 lines; thread (u, k1 in 0..7) does 8 elements.
// US = line stride, NS = element stride. Barrier-ful (R9 discipline).
template<int US, int NS, bool FUSEW>
__device__ void fwd_pass8(float2* z, const float2* __restrict__ wf, int u, int k1,
                          float c1r, float c1i, float s2,
                          float w8x, float w8y, float2 Wb)
{
    const int B = u * US;
    float2 y[8];
    float twr = 1.f, twi = 0.f;
#pragma unroll
    for (int n2 = 0; n2 < 8; ++n2) {
        float2 b = cross8(z[B + n2 * NS],        z[B + (n2 +  8) * NS],
                          z[B + (n2 + 16) * NS], z[B + (n2 + 24) * NS],
                          z[B + (n2 + 32) * NS], z[B + (n2 + 40) * NS],
                          z[B + (n2 + 48) * NS], z[B + (n2 + 56) * NS],
                          s2, c1r, c1i, w8x, w8y);
        y[n2].x = twr * b.x - twi * b.y;       // * W64^{k1*n2}
        y[n2].y = twr * b.y + twi * b.x;
        float t = twr * Wb.x - twi * Wb.y;
        twi = twr * Wb.y + twi * Wb.x;
        twr = t;
    }
    fft8_fwd(y);
    if (FUSEW) {
#pragma unroll
        for (int p = 0; p < 8; ++p) {
            float2 wv = wf[(8 * k1 + p) * 64 + u];
            cmul_ip(y[p], wv.x, wv.y);
        }
    }
    __syncthreads();   // all gathers complete before anyone overwrites
#pragma unroll
    for (int p = 0; p < 8; ++p) z[B + (8 * k1 + p) * NS] = y[p];
    __syncthreads();
}

// Inverse 64-pt: own slots -> ifft8 -> conj tw -> own slots -> gather ->
// conj cross radix-8 -> natural.
template<int US, int NS>
__device__ void inv_pass8(float2* z, int u, int k1,
                          float c1r, float c1i, float s2,
                          float w8x, float w8y, float2 Wbc)
{
    const int B = u * US;
    float2 y[8];
#pragma unroll
    for (int p = 0; p < 8; ++p) y[p] = z[B + (8 * k1 + p) * NS];
    fft8_inv(y);
    float twr = 1.f, twi = 0.f;
#pragma unroll
    for (int n2 = 0; n2 < 8; ++n2) {
        cmul_ip(y[n2], twr, twi);
        float t = twr * Wbc.x - twi * Wbc.y;
        twi = twr * Wbc.y + twi * Wbc.x;
        twr = t;
    }
#pragma unroll
    for (int n2 = 0; n2 < 8; ++n2) z[B + (8 * k1 + n2) * NS] = y[n2]; // own slots
    __syncthreads();
    float2 xx[8];
#pragma unroll
    for (int n2 = 0; n2 < 8; ++n2) {
        xx[n2] = cross8(z[B + n2 * NS],        z[B + (n2 +  8) * NS],
                        z[B + (n2 + 16) * NS], z[B + (n2 + 24) * NS],
                        z[B + (n2 + 32) * NS], z[B + (n2 + 40) * NS],
                        z[B + (n2 + 48) * NS], z[B + (n2 + 56) * NS],
                        s2, c1r, c1i, w8x, w8y);   // conj consts from caller
    }
    __syncthreads();
#pragma unroll
    for (int n2 = 0; n2 < 8; ++n2) z[B + (8 * k1 + n2) * NS] = xx[n2];
    __syncthreads();
}

// Fused slow pass: fwd(cols) + W + inv(cols); the slot round-trip between
// fwd and inv stays in registers (same thread, same addresses: risk-free).
__device__ __forceinline__ void pass_slow8(float2* z, const float2* __restrict__ wf,
        int u, int k1, float c1r, float c1i, float ci1r, float ci1i, float s2,
        float w8x, float w8y, float w8cx, float w8cy, float2 Wb, float2 Wbc)
{
    float2 y[8];
    {
        float twr = 1.f, twi = 0.f;
#pragma unroll
        for (int n2 = 0; n2 < 8; ++n2) {
            float2 b = cross8(z[u + n2 * CP],        z[u + (n2 +  8) * CP],
                              z[u + (n2 + 16) * CP], z[u + (n2 + 24) * CP],
                              z[u + (n2 + 32) * CP], z[u + (n2 + 40) * CP],
                              z[u + (n2 + 48) * CP], z[u + (n2 + 56) * CP],
                              s2, c1r, c1i, w8x, w8y);
            y[n2].x = twr * b.x - twi * b.y;
            y[n2].y = twr * b.y + twi * b.x;
            float t = twr * Wb.x - twi * Wb.y;
            twi = twr * Wb.y + twi * Wb.x;
            twr = t;
        }
    }
    fft8_fwd(y);
#pragma unroll
    for (int p = 0; p < 8; ++p) {
        float2 wv = wf[(8 * k1 + p) * 64 + u];
        cmul_ip(y[p], wv.x, wv.y);
    }
    fft8_inv(y);
    {
        float twr = 1.f, twi = 0.f;
#pragma unroll
        for (int n2 = 0; n2 < 8; ++n2) {
            cmul_ip(y[n2], twr, twi);
            float t = twr * Wbc.x - twi * Wbc.y;
            twi = twr * Wbc.y + twi * Wbc.x;
            twr = t;
        }
    }
    __syncthreads();   // all column gathers complete before overwrite
#pragma unroll
    for (int n2 = 0; n2 < 8; ++n2) z[u + (8 * k1 + n2) * CP] = y[n2]; // own slots
    __syncthreads();
    float2 xx[8];
#pragma unroll
    for (int n2 = 0; n2 < 8; ++n2) {
        xx[n2] = cross8(z[u + n2 * CP],        z[u + (n2 +  8) * CP],
                        z[u + (n2 + 16) * CP], z[u + (n2 + 24) * CP],
                        z[u + (n2 + 32) * CP], z[u + (n2 + 40) * CP],
                        z[u + (n2 + 48) * CP], z[u + (n2 + 56) * CP],
                        s2, ci1r, ci1i, w8cx, w8cy);
    }
    __syncthreads();
#pragma unroll
    for (int n2 = 0; n2 < 8; ++n2) z[u + (8 * k1 + n2) * CP] = xx[n2]; // natural
    __syncthreads();
}

// Packed per-row-pair conv, 512 threads (8 waves on one 33KB tile -> 4
// blocks/CU = 32 waves/CU, double the radix-4x16 occupancy cap).
// Optional s[I]*s[K] scaling (sstd); optional fused normalize (rstd).
// Last block handles the mean path.
__global__ __launch_bounds__(512, 8)
void row_conv2_kernel(const float* __restrict__ in, float* __restrict__ out,
                      const float2* __restrict__ wfft_br,
                      const float* __restrict__ sstd,
                      const float* __restrict__ rstd,
                      const float* __restrict__ mean_i,
                      float* __restrict__ mean_o)
{
    __shared__ float2 z[64 * CP];
    const int tid = threadIdx.x;
    const int u   = ((tid >> 6) << 3) | (tid & 7);
    const int k1  = (tid >> 3) & 7;
    const int k14 = k1 & 3;
    const float c1r = (k14 == 0) ? 1.f : ((k14 == 2) ? -1.f : 0.f);
    const float c1i = (k14 == 1) ? -1.f : ((k14 == 3) ? 1.f : 0.f);
    const float s2  = (k1 & 1) ? -1.f : 1.f;
    const float a8  = -0.7853981633974483f * (float)k1;    // -pi/4 * k1
    const float w8x = cosf(a8), w8y = sinf(a8);
    const float ang = -0.09817477042468103f * (float)k1;   // -2pi/64 * k1
    const float2 Wb  = make_float2(cosf(ang), sinf(ang));
    const float2 Wbc = make_float2(Wb.x, -Wb.y);
    const float ci1r = c1r, ci1i = -c1i;
    const float w8cx = w8x, w8cy = -w8y;

    const float* ip = in;
    float*       op = out;
    const float* sstdp = sstd;
    const float* rstdp = rstd;
    int bid = blockIdx.x;
    if (mean_i && bid == (int)gridDim.x - 1) {
        ip = mean_i; op = mean_o; sstdp = nullptr; rstdp = nullptr; bid = 0;
    }

    const int row0 = 2 * bid;
    const long long off0 = (long long)row0 * NN, off1 = off0 + NN;
    const int b   = row0 >> 12;
    const int rI0 = row0 & (NN - 1), rI1 = rI0 + 1;
    const float* sb = nullptr;
    float sI0 = 1.f, sI1 = 1.f;
    if (sstdp) { sb = sstdp + (long long)b * NN; sI0 = sb[rI0]; sI1 = sb[rI1]; }

    // batched loads: all global reads in flight before any LDS write
    float4 a4[2], c4[2], s4[2];
#pragma unroll
    for (int i = 0; i < 2; ++i) {
        int p = (tid + 512 * i) * 4;
        a4[i] = *(const float4*)(ip + off0 + p);
        c4[i] = *(const float4*)(ip + off1 + p);
    }
    if (sb) {
#pragma unroll
        for (int i = 0; i < 2; ++i) {
            int p = (tid + 512 * i) * 4;
            s4[i] = *(const float4*)(sb + p);
        }
    }
#pragma unroll
    for (int i = 0; i < 2; ++i) {
        int p = (tid + 512 * i) * 4;
        int r = p >> 6, c = p & 63;
        float4 a = a4[i], cc = c4[i];
        if (sb) {
            float4 s = s4[i];
            a.x *= sI0 * s.x; a.y *= sI0 * s.y; a.z *= sI0 * s.z; a.w *= sI0 * s.w;
            cc.x *= sI1 * s.x; cc.y *= sI1 * s.y; cc.z *= sI1 * s.z; cc.w *= sI1 * s.w;
        }
        float2* zp = z + r * CP + c;
        zp[0] = make_float2(a.x, cc.x);
        zp[1] = make_float2(a.y, cc.y);
        zp[2] = make_float2(a.z, cc.z);
        zp[3] = make_float2(a.w, cc.w);
    }
    __syncthreads();

    fwd_pass8<CP, 1, false>(z, nullptr, u, k1, c1r, c1i, s2, w8x, w8y, Wb); // fast
    pass_slow8(z, wfft_br, u, k1, c1r, c1i, ci1r, ci1i, s2,
               w8x, w8y, w8cx, w8cy, Wb, Wbc);                              // slow+W
    inv_pass8<CP, 1>(z, u, k1, ci1r, ci1i, s2, w8cx, w8cy, Wbc);            // fast

    const float scale = 1.0f / 4096.0f;
    float s0 = scale, s1 = scale;
    const float* rsb = nullptr;
    if (rstdp) {
        rsb = rstdp + (long long)b * NN;
        s0 *= rsb[rI0];
        s1 *= rsb[rI1];
    }
#pragma unroll
    for (int i = 0; i < 2; ++i) {
        int p = (tid + 512 * i) * 4;
        int r = p >> 6, c = p & 63;
        const float2* zp = z + r * CP + c;
        float4 a, cc;
        a.x = zp[0].x; a.y = zp[1].x; a.z = zp[2].x; a.w = zp[3].x;
        cc.x = zp[0].y; cc.y = zp[1].y; cc.z = zp[2].y; cc.w = zp[3].y;
        if (rsb) {
            float4 rc = *(const float4*)(rsb + p);
            a.x *= s0 * rc.x; a.y *= s0 * rc.y; a.z *= s0 * rc.z; a.w *= s0 * rc.w;
            cc.x *= s1 * rc.x; cc.y *= s1 * rc.y; cc.z *= s1 * rc.z; cc.w *= s1 * rc.w;
        } else {
            a.x *= s0; a.y *= s0; a.z *= s0; a.w *= s0;
            cc.x *= s1; cc.y *= s1; cc.z *= s1; cc.w *= s1;
        }
        *(float4*)(op + off0 + p) = a;
        *(float4*)(op + off1 + p) = cc;
    }
}

// wfft in the transform layout, via the SAME radix-8 forward passes (layouts
// match by construction). Also zeroes the var accumulator.
__global__ __launch_bounds__(512, 8)
void wfft_kernel(const float* __restrict__ w, float2* wfft_br,
                 float* __restrict__ var_zero)
{
    __shared__ float2 z[64 * CP];
    const int tid = threadIdx.x;
#pragma unroll
    for (int i = 0; i < 16; ++i) var_zero[tid + 512 * i] = 0.f;
    const int u   = ((tid >> 6) << 3) | (tid & 7);
    const int k1  = (tid >> 3) & 7;
    const int k14 = k1 & 3;
    const float c1r = (k14 == 0) ? 1.f : ((k14 == 2) ? -1.f : 0.f);
    const float c1i = (k14 == 1) ? -1.f : ((k14 == 3) ? 1.f : 0.f);
    const float s2  = (k1 & 1) ? -1.f : 1.f;
    const float a8  = -0.7853981633974483f * (float)k1;
    const float w8x = cosf(a8), w8y = sinf(a8);
    const float ang = -0.09817477042468103f * (float)k1;
    const float2 Wb = make_float2(cosf(ang), sinf(ang));

#pragma unroll
    for (int i = 0; i < 8; ++i) {
        int p = tid + 512 * i;
        z[(p >> 6) * CP + (p & 63)] = make_float2(w[p], 0.f);
    }
    __syncthreads();
    fwd_pass8<CP, 1, false>(z, nullptr, u, k1, c1r, c1i, s2, w8x, w8y, Wb);
    fwd_pass8<1, CP, false>(z, nullptr, u, k1, c1r, c1i, s2, w8x, w8y, Wb);
#pragma unroll
    for (int i = 0; i < 8; ++i) {
        int p = tid + 512 * i;
        wfft_br[p] = z[(p >> 6) * CP + (p & 63)];
    }
}

// In-place per-batch transpose of X1, TRIANGULAR grid, batched float4 I/O,
// FUSED diag (var) partials via 64-tap circular correlation w/ weight row.
__global__ __launch_bounds__(256, 4)
void transpose_inplace_kernel(float* data, const float* __restrict__ weight,
                              float* __restrict__ var)
{
    const int l = blockIdx.x;            // 0..2079 triangular index
    int bx = (int)((sqrtf(8.f * (float)l + 1.f) - 1.f) * 0.5f);
    while ((bx + 1) * (bx + 2) / 2 <= l) ++bx;   // fp guard
    while (bx * (bx + 1) / 2 > l) --bx;
    const int by = l - bx * (bx + 1) / 2;
    const int b  = blockIdx.y;

    __shared__ float tA[64 * 65];
    __shared__ float tB[64 * 65];
    __shared__ float wAs[64], wBs[64];
    __shared__ float red[512];
    const int tid = threadIdx.x;
    const int f  = tid & 15;
    const int r0 = tid >> 4;
    long long base = (long long)b * NN * NN;
    float* A  = data + base + (long long)(by * 64) * NN + bx * 64;
    float* Bt = data + base + (long long)(bx * 64) * NN + by * 64;

    if (tid < 64)       wAs[tid]      = weight[(((bx - by) & 63) << 6) + tid];
    else if (tid < 128) wBs[tid - 64] = weight[(((by - bx) & 63) << 6) + (tid - 64)];

    const int c = tid & 63, q = tid >> 6;

    if (bx == by) {
        float4 va[4];
#pragma unroll
        for (int it = 0; it < 4; ++it) {
            int r = r0 + 16 * it;
            va[it] = *(const float4*)(A + (long long)r * NN + 4 * f);
        }
#pragma unroll
        for (int it = 0; it < 4; ++it) {
            int r = r0 + 16 * it;
            tA[(4 * f + 0) * 65 + r] = va[it].x; tA[(4 * f + 1) * 65 + r] = va[it].y;
            tA[(4 * f + 2) * 65 + r] = va[it].z; tA[(4 * f + 3) * 65 + r] = va[it].w;
        }
        __syncthreads();
        float4 ov[4];
#pragma unroll
        for (int it = 0; it < 4; ++it) {
            int cc = r0 + 16 * it;
            ov[it].x = tA[cc * 65 + 4 * f + 0]; ov[it].y = tA[cc * 65 + 4 * f + 1];
            ov[it].z = tA[cc * 65 + 4 * f + 2]; ov[it].w = tA[cc * 65 + 4 * f + 3];
        }
        float sA = 0.f;
#pragma unroll
        for (int k = 0; k < 16; ++k) {
            int r = q * 16 + k;
            sA = fmaf(wAs[(c - r) & 63], tA[c * 65 + r], sA);
        }
        red[tid] = sA;
        __syncthreads();
        if (tid < 64) {
            float v = red[tid] + red[tid + 64] + red[tid + 128] + red[tid + 192];
            atomicAdd(&var[(long long)b * NN + bx * 64 + tid], v);
        }
#pragma unroll
        for (int it = 0; it < 4; ++it) {
            int cc = r0 + 16 * it;
            *(float4*)(A + (long long)cc * NN + 4 * f) = ov[it];
        }
    } else {
        float4 va[4], wb[4];
#pragma unroll
        for (int it = 0; it < 4; ++it) {
            int r = r0 + 16 * it;
            va[it] = *(const float4*)(A  + (long long)r * NN + 4 * f);
            wb[it] = *(const float4*)(Bt + (long long)r * NN + 4 * f);
        }
#pragma unroll
        for (int it = 0; it < 4; ++it) {
            int r = r0 + 16 * it;
            tA[(4 * f + 0) * 65 + r] = va[it].x; tA[(4 * f + 1) * 65 + r] = va[it].y;
            tA[(4 * f + 2) * 65 + r] = va[it].z; tA[(4 * f + 3) * 65 + r] = va[it].w;
            tB[(4 * f + 0) * 65 + r] = wb[it].x; tB[(4 * f + 1) * 65 + r] = wb[it].y;
            tB[(4 * f + 2) * 65 + r] = wb[it].z; tB[(4 * f + 3) * 65 + r] = wb[it].w;
        }
        __syncthreads();
        float4 ov[4], ow[4];
#pragma unroll
        for (int it = 0; it < 4; ++it) {
            int cc = r0 + 16 * it;
            ov[it].x = tB[cc * 65 + 4 * f + 0]; ov[it].y = tB[cc * 65 + 4 * f + 1];
            ov[it].z = tB[cc * 65 + 4 * f + 2]; ov[it].w = tB[cc * 65 + 4 * f + 3];
            ow[it].x = tA[cc * 65 + 4 * f + 0]; ow[it].y = tA[cc * 65 + 4 * f + 1];
            ow[it].z = tA[cc * 65 + 4 * f + 2]; ow[it].w = tA[cc * 65 + 4 * f + 3];
        }
        float sA = 0.f, sB = 0.f;
#pragma unroll
        for (int k = 0; k < 16; ++k) {
            int r = q * 16 + k;
            sA = fmaf(wAs[(c - r) & 63], tA[c * 65 + r], sA);
            sB = fmaf(wBs[(c - r) & 63], tB[c * 65 + r], sB);
        }
        red[tid] = sA; red[256 + tid] = sB;
        __syncthreads();
        if (tid < 64) {
            float v = red[tid] + red[tid + 64] + red[tid + 128] + red[tid + 192];
            atomicAdd(&var[(long long)b * NN + bx * 64 + tid], v);
        } else if (tid < 128) {
            int t = tid - 64;
            float v = red[256 + t] + red[320 + t] + red[384 + t] + red[448 + t];
            atomicAdd(&var[(long long)b * NN + by * 64 + t], v);
        }
#pragma unroll
        for (int it = 0; it < 4; ++it) {
            int cc = r0 + 16 * it;
            *(float4*)(A  + (long long)cc * NN + 4 * f) = ov[it];
            *(float4*)(Bt + (long long)cc * NN + 4 * f) = ow[it];
        }
    }
}

__global__ __launch_bounds__(256)
void std_kernel(const float* __restrict__ var, float* std_out, float* rstd, int n)
{
    int i = blockIdx.x * 256 + threadIdx.x;
    if (i < n) {
        float s = sqrtf(fmaxf(var[i], 1e-12f));
        std_out[i] = s;
        rstd[i] = 1.0f / s;
    }
}

extern "C" void kernel_launch(void* const* d_in, const int* in_sizes, int n_in,
                              void* d_out, int out_size, void* d_ws, size_t ws_size,
                              hipStream_t stream)
{
    const float* mean_in = (const float*)d_in[0];   // [2][64][64]
    const float* std_in  = (const float*)d_in[1];   // [2][64][64]
    const float* corr_in = (const float*)d_in[2];   // [2][4096][4096]
    const float* weight  = (const float*)d_in[3];   // [64][64]

    float* out      = (float*)d_out;
    float* mean_out = out;               // 8192
    float* std_out  = out + 8192;        // 8192
    float* corr_out = out + 16384;       // 2*4096*4096

    float*  ws      = (float*)d_ws;
    float2* wfft_br = (float2*)ws;       // 4096 float2 (8192 floats)
    float*  var_ws  = ws + 8192;         // 8192 floats
    float*  rstd_ws = ws + 16384;        // 8192 floats

    // D1: wfft + var-accumulator zeroing
    wfft_kernel<<<1, 512, 0, stream>>>(weight, wfft_br, var_ws);

    // D2 (K1): conv along K for every row pair (s[I]*s[K] scaling) -> X1.
    // Last block handles the mean path.
    row_conv2_kernel<<<NB * NN / 2 + 1, 512, 0, stream>>>(
        corr_in, corr_out, wfft_br, std_in, nullptr, mean_in, mean_out);

    // D3 (K2): in-place transpose -> X1^T, fused diag-of-cov, triangular grid
    transpose_inplace_kernel<<<dim3(2080, NB), 256, 0, stream>>>(corr_out, weight,
                                                                 var_ws);

    // D4: std/rstd from the diagonal
    std_kernel<<<(NB * NN + 255) / 256, 256, 0, stream>>>(var_ws, std_out,
                                                          rstd_ws, NB * NN);

    // D5 (K3): conv along I, in place, fused normalize via rstd_ws.
    // Symmetry: no final transpose.
    row_conv2_kernel<<<NB * NN / 2, 512, 0, stream>>>(
        corr_out, corr_out, wfft_br, nullptr, rstd_ws, nullptr, nullptr);
}

// Round 13
// 460.423 us; speedup vs baseline: 1.6063x; 1.6063x over previous
//
#include <hip/hip_runtime.h>
#include <math.h>

#define DXY   64
#define NN    4096      // 64*64
#define NB    2
#define CP    65        // LDS complex pitch (2-way conflicts free; R5 vs R7 A/B)

#define R22 0.7071067811865476f

__device__ __forceinline__ void cmul_ip(float2& a, float wr, float wi) {
    float t = a.x * wr - a.y * wi;
    a.y = a.x * wi + a.y * wr;
    a.x = t;
}

// DIF radix-2 butterfly: [a,b] -> [a+b, (a-b)*w]
__device__ __forceinline__ void bf2(float2& a, float2& b, float wr, float wi) {
    float tr = a.x - b.x, ti = a.y - b.y;
    a.x += b.x; a.y += b.y;
    b.x = tr * wr - ti * wi;
    b.y = tr * wi + ti * wr;
}
// inverse butterfly (caller passes conj tw): b'=b*w; [a,b] -> [a+b', a-b']
__device__ __forceinline__ void ibf2(float2& a, float2& b, float wr, float wi) {
    float br = b.x * wr - b.y * wi, bi = b.x * wi + b.y * wr;
    b.x = a.x - br; b.y = a.y - bi;
    a.x += br; a.y += bi;
}

// 8-pt DIF FFT, natural in -> bit-reversed out
__device__ __forceinline__ void fft8_fwd(float2* y) {
    bf2(y[0], y[4], 1.f, 0.f);  bf2(y[1], y[5],  R22, -R22);
    bf2(y[2], y[6], 0.f, -1.f); bf2(y[3], y[7], -R22, -R22);
    bf2(y[0], y[2], 1.f, 0.f);  bf2(y[1], y[3], 0.f, -1.f);
    bf2(y[4], y[6], 1.f, 0.f);  bf2(y[5], y[7], 0.f, -1.f);
    bf2(y[0], y[1], 1.f, 0.f);  bf2(y[2], y[3], 1.f, 0.f);
    bf2(y[4], y[5], 1.f, 0.f);  bf2(y[6], y[7], 1.f, 0.f);
}
// exact unscaled inverse (consumes fwd layout) = 8 * IDFT8
__device__ __forceinline__ void fft8_inv(float2* y) {
    ibf2(y[0], y[1], 1.f, 0.f); ibf2(y[2], y[3], 1.f, 0.f);
    ibf2(y[4], y[5], 1.f, 0.f); ibf2(y[6], y[7], 1.f, 0.f);
    ibf2(y[0], y[2], 1.f, 0.f); ibf2(y[1], y[3], 0.f, 1.f);
    ibf2(y[4], y[6], 1.f, 0.f); ibf2(y[5], y[7], 0.f, 1.f);
    ibf2(y[0], y[4], 1.f, 0.f); ibf2(y[1], y[5],  R22,  R22);
    ibf2(y[2], y[6], 0.f, 1.f); ibf2(y[3], y[7], -R22,  R22);
}

// Cross radix-8 combine: returns sum_j x_j * W8^{j*k1}, parameterized by
// s2 = W8^{4k1} (=+-1), c1 = W8^{2k1}, w8 = W8^{k1}. Conj consts -> inverse.
__device__ __forceinline__ float2 cross8(
    float2 x0, float2 x1, float2 x2, float2 x3,
    float2 x4, float2 x5, float2 x6, float2 x7,
    float s2, float c1r, float c1i, float w8x, float w8y)
{
    float e0r = fmaf(s2, x4.x, x0.x), e0i = fmaf(s2, x4.y, x0.y);
    float e1r = fmaf(s2, x5.x, x1.x), e1i = fmaf(s2, x5.y, x1.y);
    float e2r = fmaf(s2, x6.x, x2.x), e2i = fmaf(s2, x6.y, x2.y);
    float e3r = fmaf(s2, x7.x, x3.x), e3i = fmaf(s2, x7.y, x3.y);
    float f0r = e0r + c1r * e2r - c1i * e2i;
    float f0i = e0i + c1r * e2i + c1i * e2r;
    float f1r = e1r + c1r * e3r - c1i * e3i;
    float f1i = e1i + c1r * e3i + c1i * e3r;
    float2 o;
    o.x = f0r + w8x * f1r - w8y * f1i;
    o.y = f0i + w8x * f1i + w8y * f1r;
    return o;
}

// Forward 64-pt over 64 lines; thread (u, k1 in 0..7) does 8 elements.
// US = line stride, NS = element stride. Barrier-ful (R9 discipline).
template<int US, int NS, bool FUSEW>
__device__ void fwd_pass8(float2* z, const float2* __restrict__ wf, int u, int k1,
                          float c1r, float c1i, float s2,
                          float w8x, float w8y, float2 Wb)
{
    const int B = u * US;
    float2 y[8];
    float twr = 1.f, twi = 0.f;
#pragma unroll
    for (int n2 = 0; n2 < 8; ++n2) {
        float2 b = cross8(z[B + n2 * NS],        z[B + (n2 +  8) * NS],
                          z[B + (n2 + 16) * NS], z[B + (n2 + 24) * NS],
                          z[B + (n2 + 32) * NS], z[B + (n2 + 40) * NS],
                          z[B + (n2 + 48) * NS], z[B + (n2 + 56) * NS],
                          s2, c1r, c1i, w8x, w8y);
        y[n2].x = twr * b.x - twi * b.y;       // * W64^{k1*n2}
        y[n2].y = twr * b.y + twi * b.x;
        float t = twr * Wb.x - twi * Wb.y;
        twi = twr * Wb.y + twi * Wb.x;
        twr = t;
    }
    fft8_fwd(y);
    if (FUSEW) {
#pragma unroll
        for (int p = 0; p < 8; ++p) {
            float2 wv = wf[(8 * k1 + p) * 64 + u];
            cmul_ip(y[p], wv.x, wv.y);
        }
    }
    __syncthreads();   // all gathers complete before anyone overwrites
#pragma unroll
    for (int p = 0; p < 8; ++p) z[B + (8 * k1 + p) * NS] = y[p];
    __syncthreads();
}

// Inverse 64-pt: own slots -> ifft8 -> conj tw -> own slots -> gather ->
// conj cross radix-8 -> natural.
template<int US, int NS>
__device__ void inv_pass8(float2* z, int u, int k1,
                          float c1r, float c1i, float s2,
                          float w8x, float w8y, float2 Wbc)
{
    const int B = u * US;
    float2 y[8];
#pragma unroll
    for (int p = 0; p < 8; ++p) y[p] = z[B + (8 * k1 + p) * NS];
    fft8_inv(y);
    float twr = 1.f, twi = 0.f;
#pragma unroll
    for (int n2 = 0; n2 < 8; ++n2) {
        cmul_ip(y[n2], twr, twi);
        float t = twr * Wbc.x - twi * Wbc.y;
        twi = twr * Wbc.y + twi * Wbc.x;
        twr = t;
    }
#pragma unroll
    for (int n2 = 0; n2 < 8; ++n2) z[B + (8 * k1 + n2) * NS] = y[n2]; // own slots
    __syncthreads();
    float2 xx[8];
#pragma unroll
    for (int n2 = 0; n2 < 8; ++n2) {
        xx[n2] = cross8(z[B + n2 * NS],        z[B + (n2 +  8) * NS],
                        z[B + (n2 + 16) * NS], z[B + (n2 + 24) * NS],
                        z[B + (n2 + 32) * NS], z[B + (n2 + 40) * NS],
                        z[B + (n2 + 48) * NS], z[B + (n2 + 56) * NS],
                        s2, c1r, c1i, w8x, w8y);   // conj consts from caller
    }
    __syncthreads();
#pragma unroll
    for (int n2 = 0; n2 < 8; ++n2) z[B + (8 * k1 + n2) * NS] = xx[n2];
    __syncthreads();
}

// Fused slow pass: fwd(cols) + W + inv(cols); the slot round-trip between
// fwd and inv stays in registers (same thread, same addresses: risk-free).
__device__ __forceinline__ void pass_slow8(float2* z, const float2* __restrict__ wf,
        int u, int k1, float c1r, float c1i, float ci1r, float ci1i, float s2,
        float w8x, float w8y, float w8cx, float w8cy, float2 Wb, float2 Wbc)
{
    float2 y[8];
    {
        float twr = 1.f, twi = 0.f;
#pragma unroll
        for (int n2 = 0; n2 < 8; ++n2) {
            float2 b = cross8(z[u + n2 * CP],        z[u + (n2 +  8) * CP],
                              z[u + (n2 + 16) * CP], z[u + (n2 + 24) * CP],
                              z[u + (n2 + 32) * CP], z[u + (n2 + 40) * CP],
                              z[u + (n2 + 48) * CP], z[u + (n2 + 56) * CP],
                              s2, c1r, c1i, w8x, w8y);
            y[n2].x = twr * b.x - twi * b.y;
            y[n2].y = twr * b.y + twi * b.x;
            float t = twr * Wb.x - twi * Wb.y;
            twi = twr * Wb.y + twi * Wb.x;
            twr = t;
        }
    }
    fft8_fwd(y);
#pragma unroll
    for (int p = 0; p < 8; ++p) {
        float2 wv = wf[(8 * k1 + p) * 64 + u];
        cmul_ip(y[p], wv.x, wv.y);
    }
    fft8_inv(y);
    {
        float twr = 1.f, twi = 0.f;
#pragma unroll
        for (int n2 = 0; n2 < 8; ++n2) {
            cmul_ip(y[n2], twr, twi);
            float t = twr * Wbc.x - twi * Wbc.y;
            twi = twr * Wbc.y + twi * Wbc.x;
            twr = t;
        }
    }
    __syncthreads();   // all column gathers complete before overwrite
#pragma unroll
    for (int n2 = 0; n2 < 8; ++n2) z[u + (8 * k1 + n2) * CP] = y[n2]; // own slots
    __syncthreads();
    float2 xx[8];
#pragma unroll
    for (int n2 = 0; n2 < 8; ++n2) {
        xx[n2] = cross8(z[u + n2 * CP],        z[u + (n2 +  8) * CP],
                        z[u + (n2 + 16) * CP], z[u + (n2 + 24) * CP],
                        z[u + (n2 + 32) * CP], z[u + (n2 + 40) * CP],
                        z[u + (n2 + 48) * CP], z[u + (n2 + 56) * CP],
                        s2, ci1r, ci1i, w8cx, w8cy);
    }
    __syncthreads();
#pragma unroll
    for (int n2 = 0; n2 < 8; ++n2) z[u + (8 * k1 + n2) * CP] = xx[n2]; // natural
    __syncthreads();
}

// Packed per-row-pair conv, 512 threads. R12 lesson: __launch_bounds__(512,8)
// was interpreted as 8 BLOCKS/CU (VGPR crushed to 32 -> 900MB/dispatch spill).
// (512,4) gives 4 blocks x 8 waves = 32 waves/CU -> VGPR budget 64; under the
// guide's waves/EU reading it gives VGPR<=128. Either way: no spill,
// occupancy >= R9.
__global__ __launch_bounds__(512, 4)
void row_conv2_kernel(const float* __restrict__ in, float* __restrict__ out,
                      const float2* __restrict__ wfft_br,
                      const float* __restrict__ sstd,
                      const float* __restrict__ rstd,
                      const float* __restrict__ mean_i,
                      float* __restrict__ mean_o)
{
    __shared__ float2 z[64 * CP];
    const int tid = threadIdx.x;
    const int u   = ((tid >> 6) << 3) | (tid & 7);
    const int k1  = (tid >> 3) & 7;
    const int k14 = k1 & 3;
    const float c1r = (k14 == 0) ? 1.f : ((k14 == 2) ? -1.f : 0.f);
    const float c1i = (k14 == 1) ? -1.f : ((k14 == 3) ? 1.f : 0.f);
    const float s2  = (k1 & 1) ? -1.f : 1.f;
    const float a8  = -0.7853981633974483f * (float)k1;    // -pi/4 * k1
    const float w8x = cosf(a8), w8y = sinf(a8);
    const float ang = -0.09817477042468103f * (float)k1;   // -2pi/64 * k1
    const float2 Wb  = make_float2(cosf(ang), sinf(ang));
    const float2 Wbc = make_float2(Wb.x, -Wb.y);
    const float ci1r = c1r, ci1i = -c1i;
    const float w8cx = w8x, w8cy = -w8y;

    const float* ip = in;
    float*       op = out;
    const float* sstdp = sstd;
    const float* rstdp = rstd;
    int bid = blockIdx.x;
    if (mean_i && bid == (int)gridDim.x - 1) {
        ip = mean_i; op = mean_o; sstdp = nullptr; rstdp = nullptr; bid = 0;
    }

    const int row0 = 2 * bid;
    const long long off0 = (long long)row0 * NN, off1 = off0 + NN;
    const int b   = row0 >> 12;
    const int rI0 = row0 & (NN - 1), rI1 = rI0 + 1;
    const float* sb = nullptr;
    float sI0 = 1.f, sI1 = 1.f;
    if (sstdp) { sb = sstdp + (long long)b * NN; sI0 = sb[rI0]; sI1 = sb[rI1]; }

    // batched loads: all global reads in flight before any LDS write
    float4 a4[2], c4[2], s4[2];
#pragma unroll
    for (int i = 0; i < 2; ++i) {
        int p = (tid + 512 * i) * 4;
        a4[i] = *(const float4*)(ip + off0 + p);
        c4[i] = *(const float4*)(ip + off1 + p);
    }
    if (sb) {
#pragma unroll
        for (int i = 0; i < 2; ++i) {
            int p = (tid + 512 * i) * 4;
            s4[i] = *(const float4*)(sb + p);
        }
    }
#pragma unroll
    for (int i = 0; i < 2; ++i) {
        int p = (tid + 512 * i) * 4;
        int r = p >> 6, c = p & 63;
        float4 a = a4[i], cc = c4[i];
        if (sb) {
            float4 s = s4[i];
            a.x *= sI0 * s.x; a.y *= sI0 * s.y; a.z *= sI0 * s.z; a.w *= sI0 * s.w;
            cc.x *= sI1 * s.x; cc.y *= sI1 * s.y; cc.z *= sI1 * s.z; cc.w *= sI1 * s.w;
        }
        float2* zp = z + r * CP + c;
        zp[0] = make_float2(a.x, cc.x);
        zp[1] = make_float2(a.y, cc.y);
        zp[2] = make_float2(a.z, cc.z);
        zp[3] = make_float2(a.w, cc.w);
    }
    __syncthreads();

    fwd_pass8<CP, 1, false>(z, nullptr, u, k1, c1r, c1i, s2, w8x, w8y, Wb); // fast
    pass_slow8(z, wfft_br, u, k1, c1r, c1i, ci1r, ci1i, s2,
               w8x, w8y, w8cx, w8cy, Wb, Wbc);                              // slow+W
    inv_pass8<CP, 1>(z, u, k1, ci1r, ci1i, s2, w8cx, w8cy, Wbc);            // fast

    const float scale = 1.0f / 4096.0f;
    float s0 = scale, s1 = scale;
    const float* rsb = nullptr;
    if (rstdp) {
        rsb = rstdp + (long long)b * NN;
        s0 *= rsb[rI0];
        s1 *= rsb[rI1];
    }
#pragma unroll
    for (int i = 0; i < 2; ++i) {
        int p = (tid + 512 * i) * 4;
        int r = p >> 6, c = p & 63;
        const float2* zp = z + r * CP + c;
        float4 a, cc;
        a.x = zp[0].x; a.y = zp[1].x; a.z = zp[2].x; a.w = zp[3].x;
        cc.x = zp[0].y; cc.y = zp[1].y; cc.z = zp[2].y; cc.w = zp[3].y;
        if (rsb) {
            float4 rc = *(const float4*)(rsb + p);
            a.x *= s0 * rc.x; a.y *= s0 * rc.y; a.z *= s0 * rc.z; a.w *= s0 * rc.w;
            cc.x *= s1 * rc.x; cc.y *= s1 * rc.y; cc.z *= s1 * rc.z; cc.w *= s1 * rc.w;
        } else {
            a.x *= s0; a.y *= s0; a.z *= s0; a.w *= s0;
            cc.x *= s1; cc.y *= s1; cc.z *= s1; cc.w *= s1;
        }
        *(float4*)(op + off0 + p) = a;
        *(float4*)(op + off1 + p) = cc;
    }
}

// wfft in the transform layout, via the SAME radix-8 forward passes (layouts
// match by construction). Also zeroes the var accumulator.
__global__ __launch_bounds__(512, 4)
void wfft_kernel(const float* __restrict__ w, float2* wfft_br,
                 float* __restrict__ var_zero)
{
    __shared__ float2 z[64 * CP];
    const int tid = threadIdx.x;
#pragma unroll
    for (int i = 0; i < 16; ++i) var_zero[tid + 512 * i] = 0.f;
    const int u   = ((tid >> 6) << 3) | (tid & 7);
    const int k1  = (tid >> 3) & 7;
    const int k14 = k1 & 3;
    const float c1r = (k14 == 0) ? 1.f : ((k14 == 2) ? -1.f : 0.f);
    const float c1i = (k14 == 1) ? -1.f : ((k14 == 3) ? 1.f : 0.f);
    const float s2  = (k1 & 1) ? -1.f : 1.f;
    const float a8  = -0.7853981633974483f * (float)k1;
    const float w8x = cosf(a8), w8y = sinf(a8);
    const float ang = -0.09817477042468103f * (float)k1;
    const float2 Wb = make_float2(cosf(ang), sinf(ang));

#pragma unroll
    for (int i = 0; i < 8; ++i) {
        int p = tid + 512 * i;
        z[(p >> 6) * CP + (p & 63)] = make_float2(w[p], 0.f);
    }
    __syncthreads();
    fwd_pass8<CP, 1, false>(z, nullptr, u, k1, c1r, c1i, s2, w8x, w8y, Wb);
    fwd_pass8<1, CP, false>(z, nullptr, u, k1, c1r, c1i, s2, w8x, w8y, Wb);
#pragma unroll
    for (int i = 0; i < 8; ++i) {
        int p = tid + 512 * i;
        wfft_br[p] = z[(p >> 6) * CP + (p & 63)];
    }
}

// In-place per-batch transpose of X1, TRIANGULAR grid, batched float4 I/O,
// FUSED diag (var) partials via 64-tap circular correlation w/ weight row.
__global__ __launch_bounds__(256, 4)
void transpose_inplace_kernel(float* data, const float* __restrict__ weight,
                              float* __restrict__ var)
{
    const int l = blockIdx.x;            // 0..2079 triangular index
    int bx = (int)((sqrtf(8.f * (float)l + 1.f) - 1.f) * 0.5f);
    while ((bx + 1) * (bx + 2) / 2 <= l) ++bx;   // fp guard
    while (bx * (bx + 1) / 2 > l) --bx;
    const int by = l - bx * (bx + 1) / 2;
    const int b  = blockIdx.y;

    __shared__ float tA[64 * 65];
    __shared__ float tB[64 * 65];
    __shared__ float wAs[64], wBs[64];
    __shared__ float red[512];
    const int tid = threadIdx.x;
    const int f  = tid & 15;
    const int r0 = tid >> 4;
    long long base = (long long)b * NN * NN;
    float* A  = data + base + (long long)(by * 64) * NN + bx * 64;
    float* Bt = data + base + (long long)(bx * 64) * NN + by * 64;

    if (tid < 64)       wAs[tid]      = weight[(((bx - by) & 63) << 6) + tid];
    else if (tid < 128) wBs[tid - 64] = weight[(((by - bx) & 63) << 6) + (tid - 64)];

    const int c = tid & 63, q = tid >> 6;

    if (bx == by) {
        float4 va[4];
#pragma unroll
        for (int it = 0; it < 4; ++it) {
            int r = r0 + 16 * it;
            va[it] = *(const float4*)(A + (long long)r * NN + 4 * f);
        }
#pragma unroll
        for (int it = 0; it < 4; ++it) {
            int r = r0 + 16 * it;
            tA[(4 * f + 0) * 65 + r] = va[it].x; tA[(4 * f + 1) * 65 + r] = va[it].y;
            tA[(4 * f + 2) * 65 + r] = va[it].z; tA[(4 * f + 3) * 65 + r] = va[it].w;
        }
        __syncthreads();
        float4 ov[4];
#pragma unroll
        for (int it = 0; it < 4; ++it) {
            int cc = r0 + 16 * it;
            ov[it].x = tA[cc * 65 + 4 * f + 0]; ov[it].y = tA[cc * 65 + 4 * f + 1];
            ov[it].z = tA[cc * 65 + 4 * f + 2]; ov[it].w = tA[cc * 65 + 4 * f + 3];
        }
        float sA = 0.f;
#pragma unroll
        for (int k = 0; k < 16; ++k) {
            int r = q * 16 + k;
            sA = fmaf(wAs[(c - r) & 63], tA[c * 65 + r], sA);
        }
        red[tid] = sA;
        __syncthreads();
        if (tid < 64) {
            float v = red[tid] + red[tid + 64] + red[tid + 128] + red[tid + 192];
            atomicAdd(&var[(long long)b * NN + bx * 64 + tid], v);
        }
#pragma unroll
        for (int it = 0; it < 4; ++it) {
            int cc = r0 + 16 * it;
            *(float4*)(A + (long long)cc * NN + 4 * f) = ov[it];
        }
    } else {
        float4 va[4], wb[4];
#pragma unroll
        for (int it = 0; it < 4; ++it) {
            int r = r0 + 16 * it;
            va[it] = *(const float4*)(A  + (long long)r * NN + 4 * f);
            wb[it] = *(const float4*)(Bt + (long long)r * NN + 4 * f);
        }
#pragma unroll
        for (int it = 0; it < 4; ++it) {
            int r = r0 + 16 * it;
            tA[(4 * f + 0) * 65 + r] = va[it].x; tA[(4 * f + 1) * 65 + r] = va[it].y;
            tA[(4 * f + 2) * 65 + r] = va[it].z; tA[(4 * f + 3) * 65 + r] = va[it].w;
            tB[(4 * f + 0) * 65 + r] = wb[it].x; tB[(4 * f + 1) * 65 + r] = wb[it].y;
            tB[(4 * f + 2) * 65 + r] = wb[it].z; tB[(4 * f + 3) * 65 + r] = wb[it].w;
        }
        __syncthreads();
        float4 ov[4], ow[4];
#pragma unroll
        for (int it = 0; it < 4; ++it) {
            int cc = r0 + 16 * it;
            ov[it].x = tB[cc * 65 + 4 * f + 0]; ov[it].y = tB[cc * 65 + 4 * f + 1];
            ov[it].z = tB[cc * 65 + 4 * f + 2]; ov[it].w = tB[cc * 65 + 4 * f + 3];
            ow[it].x = tA[cc * 65 + 4 * f + 0]; ow[it].y = tA[cc * 65 + 4 * f + 1];
            ow[it].z = tA[cc * 65 + 4 * f + 2]; ow[it].w = tA[cc * 65 + 4 * f + 3];
        }
        float sA = 0.f, sB = 0.f;
#pragma unroll
        for (int k = 0; k < 16; ++k) {
            int r = q * 16 + k;
            sA = fmaf(wAs[(c - r) & 63], tA[c * 65 + r], sA);
            sB = fmaf(wBs[(c - r) & 63], tB[c * 65 + r], sB);
        }
        red[tid] = sA; red[256 + tid] = sB;
        __syncthreads();
        if (tid < 64) {
            float v = red[tid] + red[tid + 64] + red[tid + 128] + red[tid + 192];
            atomicAdd(&var[(long long)b * NN + bx * 64 + tid], v);
        } else if (tid < 128) {
            int t = tid - 64;
            float v = red[256 + t] + red[320 + t] + red[384 + t] + red[448 + t];
            atomicAdd(&var[(long long)b * NN + by * 64 + t], v);
        }
#pragma unroll
        for (int it = 0; it < 4; ++it) {
            int cc = r0 + 16 * it;
            *(float4*)(A  + (long long)cc * NN + 4 * f) = ov[it];
            *(float4*)(Bt + (long long)cc * NN + 4 * f) = ow[it];
        }
    }
}

__global__ __launch_bounds__(256)
void std_kernel(const float* __restrict__ var, float* std_out, float* rstd, int n)
{
    int i = blockIdx.x * 256 + threadIdx.x;
    if (i < n) {
        float s = sqrtf(fmaxf(var[i], 1e-12f));
        std_out[i] = s;
        rstd[i] = 1.0f / s;
    }
}

extern "C" void kernel_launch(void* const* d_in, const int* in_sizes, int n_in,
                              void* d_out, int out_size, void* d_ws, size_t ws_size,
                              hipStream_t stream)
{
    const float* mean_in = (const float*)d_in[0];   // [2][64][64]
    const float* std_in  = (const float*)d_in[1];   // [2][64][64]
    const float* corr_in = (const float*)d_in[2];   // [2][4096][4096]
    const float* weight  = (const float*)d_in[3];   // [64][64]

    float* out      = (float*)d_out;
    float* mean_out = out;               // 8192
    float* std_out  = out + 8192;        // 8192
    float* corr_out = out + 16384;       // 2*4096*4096

    float*  ws      = (float*)d_ws;
    float2* wfft_br = (float2*)ws;       // 4096 float2 (8192 floats)
    float*  var_ws  = ws + 8192;         // 8192 floats
    float*  rstd_ws = ws + 16384;        // 8192 floats

    // D1: wfft + var-accumulator zeroing
    wfft_kernel<<<1, 512, 0, stream>>>(weight, wfft_br, var_ws);

    // D2 (K1): conv along K for every row pair (s[I]*s[K] scaling) -> X1.
    // Last block handles the mean path.
    row_conv2_kernel<<<NB * NN / 2 + 1, 512, 0, stream>>>(
        corr_in, corr_out, wfft_br, std_in, nullptr, mean_in, mean_out);

    // D3 (K2): in-place transpose -> X1^T, fused diag-of-cov, triangular grid
    transpose_inplace_kernel<<<dim3(2080, NB), 256, 0, stream>>>(corr_out, weight,
                                                                 var_ws);

    // D4: std/rstd from the diagonal
    std_kernel<<<(NB * NN + 255) / 256, 256, 0, stream>>>(var_ws, std_out,
                                                          rstd_ws, NB * NN);

    // D5 (K3): conv along I, in place, fused normalize via rstd_ws.
    // Symmetry: no final transpose.
    row_conv2_kernel<<<NB * NN / 2, 512, 0, stream>>>(
        corr_out, corr_out, wfft_br, nullptr, rstd_ws, nullptr, nullptr);
}

// Round 14
// 452.822 us; speedup vs baseline: 1.6333x; 1.0168x over previous
//
#include <hip/hip_runtime.h>
#include <math.h>

#define DXY   64
#define NN    4096      // 64*64
#define NB    2
#define CP    66        // EVEN complex pitch: 16B-aligned float4 LDS ops everywhere.
                        // R13 lesson: conv is LDS-instruction-bound -> vectorize.

#define C16 0.9238795325112867f
#define S16 0.3826834323650898f
#define R22 0.7071067811865476f

__device__ __forceinline__ void cmul_ip(float2& a, float wr, float wi) {
    float t = a.x * wr - a.y * wi;
    a.y = a.x * wi + a.y * wr;
    a.x = t;
}

// radix-4 core in place on y[i0..i3]; inv selects +i rotation (conj core, unscaled)
__device__ __forceinline__ void bf4(float2* y, int i0, int i1, int i2, int i3, int inv) {
    float2 a0 = y[i0], a1 = y[i1], a2 = y[i2], a3 = y[i3];
    float t0r = a0.x + a2.x, t0i = a0.y + a2.y;
    float t1r = a0.x - a2.x, t1i = a0.y - a2.y;
    float t2r = a1.x + a3.x, t2i = a1.y + a3.y;
    float dr  = a1.x - a3.x, di  = a1.y - a3.y;
    float t3r, t3i;
    if (inv) { t3r = -di; t3i = dr; } else { t3r = di; t3i = -dr; }
    y[i0] = make_float2(t0r + t2r, t0i + t2i);
    y[i1] = make_float2(t1r + t3r, t1i + t3i);
    y[i2] = make_float2(t0r - t2r, t0i - t2i);
    y[i3] = make_float2(t1r - t3r, t1i - t3i);
}

// 16-pt DIF radix-4 (natural in, base-4 digit-reversed out), constant twiddles
__device__ __forceinline__ void fft16_fwd(float2* y) {
    bf4(y, 0, 4, 8, 12, 0);
    bf4(y, 1, 5, 9, 13, 0);
    cmul_ip(y[5],  C16, -S16); cmul_ip(y[9],  R22, -R22); cmul_ip(y[13],  S16, -C16);
    bf4(y, 2, 6, 10, 14, 0);
    cmul_ip(y[6],  R22, -R22); cmul_ip(y[10], 0.f, -1.f); cmul_ip(y[14], -R22, -R22);
    bf4(y, 3, 7, 11, 15, 0);
    cmul_ip(y[7],  S16, -C16); cmul_ip(y[11], -R22, -R22); cmul_ip(y[15], -C16,  S16);
    bf4(y, 0, 1, 2, 3, 0); bf4(y, 4, 5, 6, 7, 0);
    bf4(y, 8, 9, 10, 11, 0); bf4(y, 12, 13, 14, 15, 0);
}

// exact unscaled inverse of fft16_fwd (consumes its layout), = 16 * IDFT16
__device__ __forceinline__ void fft16_inv(float2* y) {
    bf4(y, 0, 1, 2, 3, 1); bf4(y, 4, 5, 6, 7, 1);
    bf4(y, 8, 9, 10, 11, 1); bf4(y, 12, 13, 14, 15, 1);
    cmul_ip(y[5],  C16,  S16); cmul_ip(y[9],  R22,  R22); cmul_ip(y[13],  S16,  C16);
    cmul_ip(y[6],  R22,  R22); cmul_ip(y[10], 0.f,  1.f); cmul_ip(y[14], -R22,  R22);
    cmul_ip(y[7],  S16,  C16); cmul_ip(y[11], -R22,  R22); cmul_ip(y[15], -C16, -S16);
    bf4(y, 0, 4, 8, 12, 1); bf4(y, 1, 5, 9, 13, 1);
    bf4(y, 2, 6, 10, 14, 1); bf4(y, 3, 7, 11, 15, 1);
}

// Gather + cross radix-4 + W64 twiddle recurrence from a CONTIGUOUS
// 64-complex line (float4 view, 32 instead of 64 LDS reads). Arithmetic is
// bit-identical to R9's element loop.
__device__ __forceinline__ void gather_cross4(const float4* lp, float2* y,
        float c1r, float c1i, float s2, float2 Wb)
{
    float twr = 1.f, twi = 0.f;
#pragma unroll
    for (int m = 0; m < 8; ++m) {
        float4 A = lp[m];          // elems 2m, 2m+1
        float4 B = lp[m + 8];      // +16
        float4 C = lp[m + 16];     // +32
        float4 D = lp[m + 24];     // +48
        {   // n2 = 2m
            float er  = fmaf(s2, C.x, A.x), ei = fmaf(s2, C.y, A.y);
            float orr = fmaf(s2, D.x, B.x), oi = fmaf(s2, D.y, B.y);
            float br = er + c1r * orr - c1i * oi;
            float bi = ei + c1r * oi + c1i * orr;
            y[2*m].x = twr * br - twi * bi;
            y[2*m].y = twr * bi + twi * br;
            float t = twr * Wb.x - twi * Wb.y;
            twi = twr * Wb.y + twi * Wb.x; twr = t;
        }
        {   // n2 = 2m+1
            float er  = fmaf(s2, C.z, A.z), ei = fmaf(s2, C.w, A.w);
            float orr = fmaf(s2, D.z, B.z), oi = fmaf(s2, D.w, B.w);
            float br = er + c1r * orr - c1i * oi;
            float bi = ei + c1r * oi + c1i * orr;
            y[2*m+1].x = twr * br - twi * bi;
            y[2*m+1].y = twr * bi + twi * br;
            float t = twr * Wb.x - twi * Wb.y;
            twi = twr * Wb.y + twi * Wb.x; twr = t;
        }
    }
}

// Conj cross radix-4 gather (no output twiddle) from a contiguous line.
__device__ __forceinline__ void gather_cross4_notw(const float4* lp, float2* xx,
        float c1r, float c1i, float s2)
{
#pragma unroll
    for (int m = 0; m < 8; ++m) {
        float4 A = lp[m];
        float4 B = lp[m + 8];
        float4 C = lp[m + 16];
        float4 D = lp[m + 24];
        {
            float er  = fmaf(s2, C.x, A.x), ei = fmaf(s2, C.y, A.y);
            float orr = fmaf(s2, D.x, B.x), oi = fmaf(s2, D.y, B.y);
            xx[2*m].x = er + c1r * orr - c1i * oi;
            xx[2*m].y = ei + c1r * oi + c1i * orr;
        }
        {
            float er  = fmaf(s2, C.z, A.z), ei = fmaf(s2, C.w, A.w);
            float orr = fmaf(s2, D.z, B.z), oi = fmaf(s2, D.w, B.w);
            xx[2*m+1].x = er + c1r * orr - c1i * oi;
            xx[2*m+1].y = ei + c1r * oi + c1i * orr;
        }
    }
}

// Dual-layout convention in ONE buffer z[64*CP]:
//   A (row-major):  logical (r,c) at z[r*CP + c]   -- rows contiguous
//   B (col-major):  logical (r,c) at z[c*CP + r]   -- columns contiguous
// A-range of line u and B-range of column u are the SAME addresses, so the
// R9 sync-before-write discipline covers all cross-layout aliasing.

// P1: fast-axis fwd. Read row u (A, f4), write slots col-major (B, lane-contig f2).
__device__ void p1_fast_fwd(float2* z, int u, int k1,
        float c1r, float c1i, float s2, float2 Wb)
{
    float2 y[16];
    gather_cross4((const float4*)(z + u * CP), y, c1r, c1i, s2, Wb);
    fft16_fwd(y);
    __syncthreads();   // all A-reads complete before B-writes clobber
#pragma unroll
    for (int p = 0; p < 16; ++p) z[(16*k1 + p) * CP + u] = y[p];
    __syncthreads();
}

// P2: slow-axis fwd + W. Column u contiguous in B -> all f4.
__device__ void p2_slow_fwd(float2* z, const float2* __restrict__ wf, int u, int k1,
        float c1r, float c1i, float s2, float2 Wb)
{
    float2 y[16];
    gather_cross4((const float4*)(z + u * CP), y, c1r, c1i, s2, Wb);
    fft16_fwd(y);
#pragma unroll
    for (int p = 0; p < 16; ++p) {
        float2 wv = wf[(16*k1 + p) * 64 + u];
        cmul_ip(y[p], wv.x, wv.y);
    }
    __syncthreads();   // all gathers complete before slot writes
    float4* slot = (float4*)(z + u * CP + 16 * k1);
#pragma unroll
    for (int j = 0; j < 8; ++j)
        slot[j] = make_float4(y[2*j].x, y[2*j].y, y[2*j+1].x, y[2*j+1].y);
    __syncthreads();
}

// P3: slow-axis inv. All in B, column u contiguous -> all f4.
__device__ void p3_slow_inv(float2* z, int u, int k1,
        float ci1r, float ci1i, float s2, float2 Wbc)
{
    float2 y[16];
    float4* slot = (float4*)(z + u * CP + 16 * k1);
#pragma unroll
    for (int j = 0; j < 8; ++j) {
        float4 v = slot[j];
        y[2*j]   = make_float2(v.x, v.y);
        y[2*j+1] = make_float2(v.z, v.w);
    }
    fft16_inv(y);
    float twr = 1.f, twi = 0.f;
#pragma unroll
    for (int n2 = 0; n2 < 16; ++n2) {
        cmul_ip(y[n2], twr, twi);
        float t = twr * Wbc.x - twi * Wbc.y;
        twi = twr * Wbc.y + twi * Wbc.x; twr = t;
    }
#pragma unroll
    for (int j = 0; j < 8; ++j)      // own slots (same addrs just read by self)
        slot[j] = make_float4(y[2*j].x, y[2*j].y, y[2*j+1].x, y[2*j+1].y);
    __syncthreads();
    float2 xx[16];
    gather_cross4_notw((const float4*)(z + u * CP), xx, ci1r, ci1i, s2);
    __syncthreads();
#pragma unroll
    for (int j = 0; j < 8; ++j)      // natural order into own slot range
        slot[j] = make_float4(xx[2*j].x, xx[2*j].y, xx[2*j+1].x, xx[2*j+1].y);
    __syncthreads();
}

// P4: fast-axis inv. Read own slots from B (strided f2), then row-major A f4.
__device__ void p4_fast_inv(float2* z, int u, int k1,
        float ci1r, float ci1i, float s2, float2 Wbc)
{
    float2 y[16];
#pragma unroll
    for (int p = 0; p < 16; ++p) y[p] = z[(16*k1 + p) * CP + u];
    fft16_inv(y);
    float twr = 1.f, twi = 0.f;
#pragma unroll
    for (int n2 = 0; n2 < 16; ++n2) {
        cmul_ip(y[n2], twr, twi);
        float t = twr * Wbc.x - twi * Wbc.y;
        twi = twr * Wbc.y + twi * Wbc.x; twr = t;
    }
    __syncthreads();   // all B-reads complete before A-writes clobber
    float4* slot = (float4*)(z + u * CP + 16 * k1);
#pragma unroll
    for (int j = 0; j < 8; ++j)
        slot[j] = make_float4(y[2*j].x, y[2*j].y, y[2*j+1].x, y[2*j+1].y);
    __syncthreads();
    float2 xx[16];
    gather_cross4_notw((const float4*)(z + u * CP), xx, ci1r, ci1i, s2);
    __syncthreads();
#pragma unroll
    for (int j = 0; j < 8; ++j)
        slot[j] = make_float4(xx[2*j].x, xx[2*j].y, xx[2*j+1].x, xx[2*j+1].y);
    __syncthreads();
}

// Packed per-row-pair conv: rows (2blk, 2blk+1) -> re/im of one complex 64x64
// 2D FFT conv. Optional s[I]*s[K] input scaling (sstd); optional fused
// normalize (rstd). Last block handles the mean path. Coalesced f4 global I/O.
__global__ __launch_bounds__(256, 4)
void row_conv2_kernel(const float* __restrict__ in, float* __restrict__ out,
                      const float2* __restrict__ wfft_br,
                      const float* __restrict__ sstd,
                      const float* __restrict__ rstd,
                      const float* __restrict__ mean_i,
                      float* __restrict__ mean_o)
{
    __shared__ float2 z[64 * CP];           // 33792 B -> 4 blocks/CU
    const int tid = threadIdx.x;
    const int u   = ((tid >> 6) << 4) | (tid & 15);
    const int k1  = (tid >> 4) & 3;
    const float c1r = (k1 == 0) ? 1.f : ((k1 == 2) ? -1.f : 0.f);
    const float c1i = (k1 == 1) ? -1.f : ((k1 == 3) ? 1.f : 0.f);
    const float s2  = (k1 & 1) ? -1.f : 1.f;
    const float ang = -0.09817477042468103f * (float)k1;   // -2pi/64 * k1
    const float2 Wb  = make_float2(cosf(ang), sinf(ang));
    const float2 Wbc = make_float2(Wb.x, -Wb.y);
    const float ci1r = c1r, ci1i = -c1i;

    const float* ip = in;
    float*       op = out;
    const float* sstdp = sstd;
    const float* rstdp = rstd;
    int bid = blockIdx.x;
    if (mean_i && bid == (int)gridDim.x - 1) {
        ip = mean_i; op = mean_o; sstdp = nullptr; rstdp = nullptr; bid = 0;
    }

    const int row0 = 2 * bid;
    const long long off0 = (long long)row0 * NN, off1 = off0 + NN;
    const int b   = row0 >> 12;
    const int rI0 = row0 & (NN - 1), rI1 = rI0 + 1;
    const float* sb = nullptr;
    float sI0 = 1.f, sI1 = 1.f;
    if (sstdp) { sb = sstdp + (long long)b * NN; sI0 = sb[rI0]; sI1 = sb[rI1]; }

    // batched loads: all global reads in flight before any LDS write
    float4 a4[4], c4[4], s4[4];
#pragma unroll
    for (int i = 0; i < 4; ++i) {
        int p = (tid + 256 * i) * 4;
        a4[i] = *(const float4*)(ip + off0 + p);
        c4[i] = *(const float4*)(ip + off1 + p);
    }
    if (sb) {
#pragma unroll
        for (int i = 0; i < 4; ++i) {
            int p = (tid + 256 * i) * 4;
            s4[i] = *(const float4*)(sb + p);
        }
    }
#pragma unroll
    for (int i = 0; i < 4; ++i) {
        int p = (tid + 256 * i) * 4;
        int r = p >> 6, c = p & 63;
        float4 a = a4[i], cc = c4[i];
        if (sb) {
            float4 s = s4[i];
            a.x *= sI0 * s.x; a.y *= sI0 * s.y; a.z *= sI0 * s.z; a.w *= sI0 * s.w;
            cc.x *= sI1 * s.x; cc.y *= sI1 * s.y; cc.z *= sI1 * s.z; cc.w *= sI1 * s.w;
        }
        float4* zp = (float4*)(z + r * CP + c);      // (r*CP+c) even -> aligned
        zp[0] = make_float4(a.x, cc.x, a.y, cc.y);
        zp[1] = make_float4(a.z, cc.z, a.w, cc.w);
    }
    __syncthreads();

    p1_fast_fwd(z, u, k1, c1r, c1i, s2, Wb);
    p2_slow_fwd(z, wfft_br, u, k1, c1r, c1i, s2, Wb);
    p3_slow_inv(z, u, k1, ci1r, ci1i, s2, Wbc);
    p4_fast_inv(z, u, k1, ci1r, ci1i, s2, Wbc);

    const float scale = 1.0f / 4096.0f;
    float s0 = scale, s1 = scale;
    const float* rsb = nullptr;
    if (rstdp) {
        rsb = rstdp + (long long)b * NN;
        s0 *= rsb[rI0];
        s1 *= rsb[rI1];
    }
#pragma unroll
    for (int i = 0; i < 4; ++i) {
        int p = (tid + 256 * i) * 4;
        int r = p >> 6, c = p & 63;
        const float4* zp = (const float4*)(z + r * CP + c);
        float4 v0 = zp[0], v1 = zp[1];
        float4 a  = make_float4(v0.x, v0.z, v1.x, v1.z);
        float4 cc = make_float4(v0.y, v0.w, v1.y, v1.w);
        if (rsb) {
            float4 rc = *(const float4*)(rsb + p);
            a.x *= s0 * rc.x; a.y *= s0 * rc.y; a.z *= s0 * rc.z; a.w *= s0 * rc.w;
            cc.x *= s1 * rc.x; cc.y *= s1 * rc.y; cc.z *= s1 * rc.z; cc.w *= s1 * rc.w;
        } else {
            a.x *= s0; a.y *= s0; a.z *= s0; a.w *= s0;
            cc.x *= s1; cc.y *= s1; cc.z *= s1; cc.w *= s1;
        }
        *(float4*)(op + off0 + p) = a;
        *(float4*)(op + off1 + p) = cc;
    }
}

// wfft in the transform layout via the SAME P1 + slow-fwd gather; the final
// spectrum is dumped straight from registers (no second LDS round trip).
// Also zeroes the var accumulator.
__global__ __launch_bounds__(256, 4)
void wfft_kernel(const float* __restrict__ w, float2* wfft_br,
                 float* __restrict__ var_zero)
{
    __shared__ float2 z[64 * CP];
    const int tid = threadIdx.x;
#pragma unroll
    for (int i = 0; i < 32; ++i) var_zero[tid + 256 * i] = 0.f;
    const int u   = ((tid >> 6) << 4) | (tid & 15);
    const int k1  = (tid >> 4) & 3;
    const float c1r = (k1 == 0) ? 1.f : ((k1 == 2) ? -1.f : 0.f);
    const float c1i = (k1 == 1) ? -1.f : ((k1 == 3) ? 1.f : 0.f);
    const float s2  = (k1 & 1) ? -1.f : 1.f;
    const float ang = -0.09817477042468103f * (float)k1;
    const float2 Wb = make_float2(cosf(ang), sinf(ang));

#pragma unroll
    for (int i = 0; i < 16; ++i) {
        int p = tid + 256 * i;
        z[(p >> 6) * CP + (p & 63)] = make_float2(w[p], 0.f);
    }
    __syncthreads();
    p1_fast_fwd(z, u, k1, c1r, c1i, s2, Wb);
    float2 y[16];
    gather_cross4((const float4*)(z + u * CP), y, c1r, c1i, s2, Wb);
    fft16_fwd(y);
#pragma unroll
    for (int p = 0; p < 16; ++p)
        wfft_br[(16 * k1 + p) * 64 + u] = y[p];   // (slot)*64 + col convention
}

// In-place per-batch transpose of X1, TRIANGULAR grid, batched float4 I/O,
// FUSED diag (var) partials via 64-tap circular correlation w/ weight row.
__global__ __launch_bounds__(256, 4)
void transpose_inplace_kernel(float* data, const float* __restrict__ weight,
                              float* __restrict__ var)
{
    const int l = blockIdx.x;            // 0..2079 triangular index
    int bx = (int)((sqrtf(8.f * (float)l + 1.f) - 1.f) * 0.5f);
    while ((bx + 1) * (bx + 2) / 2 <= l) ++bx;   // fp guard
    while (bx * (bx + 1) / 2 > l) --bx;
    const int by = l - bx * (bx + 1) / 2;
    const int b  = blockIdx.y;

    __shared__ float tA[64 * 65];
    __shared__ float tB[64 * 65];
    __shared__ float wAs[64], wBs[64];
    __shared__ float red[512];
    const int tid = threadIdx.x;
    const int f  = tid & 15;
    const int r0 = tid >> 4;
    long long base = (long long)b * NN * NN;
    float* A  = data + base + (long long)(by * 64) * NN + bx * 64;
    float* Bt = data + base + (long long)(bx * 64) * NN + by * 64;

    if (tid < 64)       wAs[tid]      = weight[(((bx - by) & 63) << 6) + tid];
    else if (tid < 128) wBs[tid - 64] = weight[(((by - bx) & 63) << 6) + (tid - 64)];

    const int c = tid & 63, q = tid >> 6;

    if (bx == by) {
        float4 va[4];
#pragma unroll
        for (int it = 0; it < 4; ++it) {
            int r = r0 + 16 * it;
            va[it] = *(const float4*)(A + (long long)r * NN + 4 * f);
        }
#pragma unroll
        for (int it = 0; it < 4; ++it) {
            int r = r0 + 16 * it;
            tA[(4 * f + 0) * 65 + r] = va[it].x; tA[(4 * f + 1) * 65 + r] = va[it].y;
            tA[(4 * f + 2) * 65 + r] = va[it].z; tA[(4 * f + 3) * 65 + r] = va[it].w;
        }
        __syncthreads();
        float4 ov[4];
#pragma unroll
        for (int it = 0; it < 4; ++it) {
            int cc = r0 + 16 * it;
            ov[it].x = tA[cc * 65 + 4 * f + 0]; ov[it].y = tA[cc * 65 + 4 * f + 1];
            ov[it].z = tA[cc * 65 + 4 * f + 2]; ov[it].w = tA[cc * 65 + 4 * f + 3];
        }
        float sA = 0.f;
#pragma unroll
        for (int k = 0; k < 16; ++k) {
            int r = q * 16 + k;
            sA = fmaf(wAs[(c - r) & 63], tA[c * 65 + r], sA);
        }
        red[tid] = sA;
        __syncthreads();
        if (tid < 64) {
            float v = red[tid] + red[tid + 64] + red[tid + 128] + red[tid + 192];
            atomicAdd(&var[(long long)b * NN + bx * 64 + tid], v);
        }
#pragma unroll
        for (int it = 0; it < 4; ++it) {
            int cc = r0 + 16 * it;
            *(float4*)(A + (long long)cc * NN + 4 * f) = ov[it];
        }
    } else {
        float4 va[4], wb[4];
#pragma unroll
        for (int it = 0; it < 4; ++it) {
            int r = r0 + 16 * it;
            va[it] = *(const float4*)(A  + (long long)r * NN + 4 * f);
            wb[it] = *(const float4*)(Bt + (long long)r * NN + 4 * f);
        }
#pragma unroll
        for (int it = 0; it < 4; ++it) {
            int r = r0 + 16 * it;
            tA[(4 * f + 0) * 65 + r] = va[it].x; tA[(4 * f + 1) * 65 + r] = va[it].y;
            tA[(4 * f + 2) * 65 + r] = va[it].z; tA[(4 * f + 3) * 65 + r] = va[it].w;
            tB[(4 * f + 0) * 65 + r] = wb[it].x; tB[(4 * f + 1) * 65 + r] = wb[it].y;
            tB[(4 * f + 2) * 65 + r] = wb[it].z; tB[(4 * f + 3) * 65 + r] = wb[it].w;
        }
        __syncthreads();
        float4 ov[4], ow[4];
#pragma unroll
        for (int it = 0; it < 4; ++it) {
            int cc = r0 + 16 * it;
            ov[it].x = tB[cc * 65 + 4 * f + 0]; ov[it].y = tB[cc * 65 + 4 * f + 1];
            ov[it].z = tB[cc * 65 + 4 * f + 2]; ov[it].w = tB[cc * 65 + 4 * f + 3];
            ow[it].x = tA[cc * 65 + 4 * f + 0]; ow[it].y = tA[cc * 65 + 4 * f + 1];
            ow[it].z = tA[cc * 65 + 4 * f + 2]; ow[it].w = tA[cc * 65 + 4 * f + 3];
        }
        float sA = 0.f, sB = 0.f;
#pragma unroll
        for (int k = 0; k < 16; ++k) {
            int r = q * 16 + k;
            sA = fmaf(wAs[(c - r) & 63], tA[c * 65 + r], sA);
            sB = fmaf(wBs[(c - r) & 63], tB[c * 65 + r], sB);
        }
        red[tid] = sA; red[256 + tid] = sB;
        __syncthreads();
        if (tid < 64) {
            float v = red[tid] + red[tid + 64] + red[tid + 128] + red[tid + 192];
            atomicAdd(&var[(long long)b * NN + bx * 64 + tid], v);
        } else if (tid < 128) {
            int t = tid - 64;
            float v = red[256 + t] + red[320 + t] + red[384 + t] + red[448 + t];
            atomicAdd(&var[(long long)b * NN + by * 64 + t], v);
        }
#pragma unroll
        for (int it = 0; it < 4; ++it) {
            int cc = r0 + 16 * it;
            *(float4*)(A  + (long long)cc * NN + 4 * f) = ov[it];
            *(float4*)(Bt + (long long)cc * NN + 4 * f) = ow[it];
        }
    }
}

__global__ __launch_bounds__(256)
void std_kernel(const float* __restrict__ var, float* std_out, float* rstd, int n)
{
    int i = blockIdx.x * 256 + threadIdx.x;
    if (i < n) {
        float s = sqrtf(fmaxf(var[i], 1e-12f));
        std_out[i] = s;
        rstd[i] = 1.0f / s;
    }
}

extern "C" void kernel_launch(void* const* d_in, const int* in_sizes, int n_in,
                              void* d_out, int out_size, void* d_ws, size_t ws_size,
                              hipStream_t stream)
{
    const float* mean_in = (const float*)d_in[0];   // [2][64][64]
    const float* std_in  = (const float*)d_in[1];   // [2][64][64]
    const float* corr_in = (const float*)d_in[2];   // [2][4096][4096]
    const float* weight  = (const float*)d_in[3];   // [64][64]

    float* out      = (float*)d_out;
    float* mean_out = out;               // 8192
    float* std_out  = out + 8192;        // 8192
    float* corr_out = out + 16384;       // 2*4096*4096

    float*  ws      = (float*)d_ws;
    float2* wfft_br = (float2*)ws;       // 4096 float2 (8192 floats)
    float*  var_ws  = ws + 8192;         // 8192 floats
    float*  rstd_ws = ws + 16384;        // 8192 floats

    // D1: wfft + var-accumulator zeroing
    wfft_kernel<<<1, 256, 0, stream>>>(weight, wfft_br, var_ws);

    // D2 (K1): conv along K for every row pair (s[I]*s[K] scaling) -> X1.
    // Last block handles the mean path.
    row_conv2_kernel<<<NB * NN / 2 + 1, 256, 0, stream>>>(
        corr_in, corr_out, wfft_br, std_in, nullptr, mean_in, mean_out);

    // D3 (K2): in-place transpose -> X1^T, fused diag-of-cov, triangular grid
    transpose_inplace_kernel<<<dim3(2080, NB), 256, 0, stream>>>(corr_out, weight,
                                                                 var_ws);

    // D4: std/rstd from the diagonal
    std_kernel<<<(NB * NN + 255) / 256, 256, 0, stream>>>(var_ws, std_out,
                                                          rstd_ws, NB * NN);

    // D5 (K3): conv along I, in place, fused normalize via rstd_ws.
    // Symmetry: no final transpose.
    row_conv2_kernel<<<NB * NN / 2, 256, 0, stream>>>(
        corr_out, corr_out, wfft_br, nullptr, rstd_ws, nullptr, nullptr);
}

// Round 15
// 412.777 us; speedup vs baseline: 1.7917x; 1.0970x over previous
//
#include <hip/hip_runtime.h>
#include <math.h>

#define DXY   64
#define NN    4096      // 64*64
#define NB    2
#define CP    66        // EVEN complex pitch: 16B-aligned float4 LDS ops everywhere.

#define C16 0.9238795325112867f
#define S16 0.3826834323650898f
#define R22 0.7071067811865476f

__device__ __forceinline__ void cmul_ip(float2& a, float wr, float wi) {
    float t = a.x * wr - a.y * wi;
    a.y = a.x * wi + a.y * wr;
    a.x = t;
}

// radix-4 core in place on y[i0..i3]; inv selects +i rotation (conj core, unscaled)
__device__ __forceinline__ void bf4(float2* y, int i0, int i1, int i2, int i3, int inv) {
    float2 a0 = y[i0], a1 = y[i1], a2 = y[i2], a3 = y[i3];
    float t0r = a0.x + a2.x, t0i = a0.y + a2.y;
    float t1r = a0.x - a2.x, t1i = a0.y - a2.y;
    float t2r = a1.x + a3.x, t2i = a1.y + a3.y;
    float dr  = a1.x - a3.x, di  = a1.y - a3.y;
    float t3r, t3i;
    if (inv) { t3r = -di; t3i = dr; } else { t3r = di; t3i = -dr; }
    y[i0] = make_float2(t0r + t2r, t0i + t2i);
    y[i1] = make_float2(t1r + t3r, t1i + t3i);
    y[i2] = make_float2(t0r - t2r, t0i - t2i);
    y[i3] = make_float2(t1r - t3r, t1i - t3i);
}

// 16-pt DIF radix-4 (natural in, base-4 digit-reversed out), constant twiddles
__device__ __forceinline__ void fft16_fwd(float2* y) {
    bf4(y, 0, 4, 8, 12, 0);
    bf4(y, 1, 5, 9, 13, 0);
    cmul_ip(y[5],  C16, -S16); cmul_ip(y[9],  R22, -R22); cmul_ip(y[13],  S16, -C16);
    bf4(y, 2, 6, 10, 14, 0);
    cmul_ip(y[6],  R22, -R22); cmul_ip(y[10], 0.f, -1.f); cmul_ip(y[14], -R22, -R22);
    bf4(y, 3, 7, 11, 15, 0);
    cmul_ip(y[7],  S16, -C16); cmul_ip(y[11], -R22, -R22); cmul_ip(y[15], -C16,  S16);
    bf4(y, 0, 1, 2, 3, 0); bf4(y, 4, 5, 6, 7, 0);
    bf4(y, 8, 9, 10, 11, 0); bf4(y, 12, 13, 14, 15, 0);
}

// exact unscaled inverse of fft16_fwd (consumes its layout), = 16 * IDFT16
__device__ __forceinline__ void fft16_inv(float2* y) {
    bf4(y, 0, 1, 2, 3, 1); bf4(y, 4, 5, 6, 7, 1);
    bf4(y, 8, 9, 10, 11, 1); bf4(y, 12, 13, 14, 15, 1);
    cmul_ip(y[5],  C16,  S16); cmul_ip(y[9],  R22,  R22); cmul_ip(y[13],  S16,  C16);
    cmul_ip(y[6],  R22,  R22); cmul_ip(y[10], 0.f,  1.f); cmul_ip(y[14], -R22,  R22);
    cmul_ip(y[7],  S16,  C16); cmul_ip(y[11], -R22,  R22); cmul_ip(y[15], -C16, -S16);
    bf4(y, 0, 4, 8, 12, 1); bf4(y, 1, 5, 9, 13, 1);
    bf4(y, 2, 6, 10, 14, 1); bf4(y, 3, 7, 11, 15, 1);
}

// Gather + cross radix-4 + W64 twiddle recurrence from a CONTIGUOUS
// 64-complex line (float4 view, 32 instead of 64 LDS reads). Arithmetic is
// bit-identical to R9's element loop.
__device__ __forceinline__ void gather_cross4(const float4* lp, float2* y,
        float c1r, float c1i, float s2, float2 Wb)
{
    float twr = 1.f, twi = 0.f;
#pragma unroll
    for (int m = 0; m < 8; ++m) {
        float4 A = lp[m];          // elems 2m, 2m+1
        float4 B = lp[m + 8];      // +16
        float4 C = lp[m + 16];     // +32
        float4 D = lp[m + 24];     // +48
        {   // n2 = 2m
            float er  = fmaf(s2, C.x, A.x), ei = fmaf(s2, C.y, A.y);
            float orr = fmaf(s2, D.x, B.x), oi = fmaf(s2, D.y, B.y);
            float br = er + c1r * orr - c1i * oi;
            float bi = ei + c1r * oi + c1i * orr;
            y[2*m].x = twr * br - twi * bi;
            y[2*m].y = twr * bi + twi * br;
            float t = twr * Wb.x - twi * Wb.y;
            twi = twr * Wb.y + twi * Wb.x; twr = t;
        }
        {   // n2 = 2m+1
            float er  = fmaf(s2, C.z, A.z), ei = fmaf(s2, C.w, A.w);
            float orr = fmaf(s2, D.z, B.z), oi = fmaf(s2, D.w, B.w);
            float br = er + c1r * orr - c1i * oi;
            float bi = ei + c1r * oi + c1i * orr;
            y[2*m+1].x = twr * br - twi * bi;
            y[2*m+1].y = twr * bi + twi * br;
            float t = twr * Wb.x - twi * Wb.y;
            twi = twr * Wb.y + twi * Wb.x; twr = t;
        }
    }
}

// Conj cross radix-4 gather (no output twiddle) from a contiguous line.
__device__ __forceinline__ void gather_cross4_notw(const float4* lp, float2* xx,
        float c1r, float c1i, float s2)
{
#pragma unroll
    for (int m = 0; m < 8; ++m) {
        float4 A = lp[m];
        float4 B = lp[m + 8];
        float4 C = lp[m + 16];
        float4 D = lp[m + 24];
        {
            float er  = fmaf(s2, C.x, A.x), ei = fmaf(s2, C.y, A.y);
            float orr = fmaf(s2, D.x, B.x), oi = fmaf(s2, D.y, B.y);
            xx[2*m].x = er + c1r * orr - c1i * oi;
            xx[2*m].y = ei + c1r * oi + c1i * orr;
        }
        {
            float er  = fmaf(s2, C.z, A.z), ei = fmaf(s2, C.w, A.w);
            float orr = fmaf(s2, D.z, B.z), oi = fmaf(s2, D.w, B.w);
            xx[2*m+1].x = er + c1r * orr - c1i * oi;
            xx[2*m+1].y = ei + c1r * oi + c1i * orr;
        }
    }
}

// Dual-layout convention in ONE buffer z[64*CP]:
//   A (row-major):  logical (r,c) at z[r*CP + c]   -- rows contiguous
//   B (col-major):  logical (r,c) at z[c*CP + r]   -- columns contiguous
// A-range of line u and B-range of column u are the SAME addresses, so the
// R9 sync-before-write discipline covers all cross-layout aliasing.

// P1: fast-axis fwd. Read row u (A, f4), write slots col-major (B, lane-contig f2).
__device__ void p1_fast_fwd(float2* z, int u, int k1,
        float c1r, float c1i, float s2, float2 Wb)
{
    float2 y[16];
    gather_cross4((const float4*)(z + u * CP), y, c1r, c1i, s2, Wb);
    fft16_fwd(y);
    __syncthreads();   // all A-reads complete before B-writes clobber
#pragma unroll
    for (int p = 0; p < 16; ++p) z[(16*k1 + p) * CP + u] = y[p];
    __syncthreads();
}

// P2: slow-axis fwd + W. Column u contiguous in B -> all f4.
__device__ void p2_slow_fwd(float2* z, const float2* __restrict__ wf, int u, int k1,
        float c1r, float c1i, float s2, float2 Wb)
{
    float2 y[16];
    gather_cross4((const float4*)(z + u * CP), y, c1r, c1i, s2, Wb);
    fft16_fwd(y);
#pragma unroll
    for (int p = 0; p < 16; ++p) {
        float2 wv = wf[(16*k1 + p) * 64 + u];
        cmul_ip(y[p], wv.x, wv.y);
    }
    __syncthreads();   // all gathers complete before slot writes
    float4* slot = (float4*)(z + u * CP + 16 * k1);
#pragma unroll
    for (int j = 0; j < 8; ++j)
        slot[j] = make_float4(y[2*j].x, y[2*j].y, y[2*j+1].x, y[2*j+1].y);
    __syncthreads();
}

// P3: slow-axis inv. All in B, column u contiguous -> all f4.
__device__ void p3_slow_inv(float2* z, int u, int k1,
        float ci1r, float ci1i, float s2, float2 Wbc)
{
    float2 y[16];
    float4* slot = (float4*)(z + u * CP + 16 * k1);
#pragma unroll
    for (int j = 0; j < 8; ++j) {
        float4 v = slot[j];
        y[2*j]   = make_float2(v.x, v.y);
        y[2*j+1] = make_float2(v.z, v.w);
    }
    fft16_inv(y);
    float twr = 1.f, twi = 0.f;
#pragma unroll
    for (int n2 = 0; n2 < 16; ++n2) {
        cmul_ip(y[n2], twr, twi);
        float t = twr * Wbc.x - twi * Wbc.y;
        twi = twr * Wbc.y + twi * Wbc.x; twr = t;
    }
#pragma unroll
    for (int j = 0; j < 8; ++j)      // own slots (same addrs just read by self)
        slot[j] = make_float4(y[2*j].x, y[2*j].y, y[2*j+1].x, y[2*j+1].y);
    __syncthreads();
    float2 xx[16];
    gather_cross4_notw((const float4*)(z + u * CP), xx, ci1r, ci1i, s2);
    __syncthreads();
#pragma unroll
    for (int j = 0; j < 8; ++j)      // natural order into own slot range
        slot[j] = make_float4(xx[2*j].x, xx[2*j].y, xx[2*j+1].x, xx[2*j+1].y);
    __syncthreads();
}

// P4: fast-axis inv. Read own slots from B (strided f2), then row-major A f4.
__device__ void p4_fast_inv(float2* z, int u, int k1,
        float ci1r, float ci1i, float s2, float2 Wbc)
{
    float2 y[16];
#pragma unroll
    for (int p = 0; p < 16; ++p) y[p] = z[(16*k1 + p) * CP + u];
    fft16_inv(y);
    float twr = 1.f, twi = 0.f;
#pragma unroll
    for (int n2 = 0; n2 < 16; ++n2) {
        cmul_ip(y[n2], twr, twi);
        float t = twr * Wbc.x - twi * Wbc.y;
        twi = twr * Wbc.y + twi * Wbc.x; twr = t;
    }
    __syncthreads();   // all B-reads complete before A-writes clobber
    float4* slot = (float4*)(z + u * CP + 16 * k1);
#pragma unroll
    for (int j = 0; j < 8; ++j)
        slot[j] = make_float4(y[2*j].x, y[2*j].y, y[2*j+1].x, y[2*j+1].y);
    __syncthreads();
    float2 xx[16];
    gather_cross4_notw((const float4*)(z + u * CP), xx, ci1r, ci1i, s2);
    __syncthreads();
#pragma unroll
    for (int j = 0; j < 8; ++j)
        slot[j] = make_float4(xx[2*j].x, xx[2*j].y, xx[2*j+1].x, xx[2*j+1].y);
    __syncthreads();
}

// Packed per-row-pair conv. R14 lesson: (256,4) empirically caps VGPR at
// 256/4 = 64 on this toolchain; the dual-layout body needs ~90-110 so it
// spilled (+170MB/dispatch scratch). (256,2) -> cap 128. LDS (33792B)
// already limits occupancy to 4 blocks/CU = 4 waves/SIMD; 4 waves x 128
// VGPR = 512 = full file, so the higher cap costs NO occupancy.
__global__ __launch_bounds__(256, 2)
void row_conv2_kernel(const float* __restrict__ in, float* __restrict__ out,
                      const float2* __restrict__ wfft_br,
                      const float* __restrict__ sstd,
                      const float* __restrict__ rstd,
                      const float* __restrict__ mean_i,
                      float* __restrict__ mean_o)
{
    __shared__ float2 z[64 * CP];           // 33792 B -> 4 blocks/CU
    const int tid = threadIdx.x;
    const int u   = ((tid >> 6) << 4) | (tid & 15);
    const int k1  = (tid >> 4) & 3;
    const float c1r = (k1 == 0) ? 1.f : ((k1 == 2) ? -1.f : 0.f);
    const float c1i = (k1 == 1) ? -1.f : ((k1 == 3) ? 1.f : 0.f);
    const float s2  = (k1 & 1) ? -1.f : 1.f;
    const float ang = -0.09817477042468103f * (float)k1;   // -2pi/64 * k1
    const float2 Wb  = make_float2(cosf(ang), sinf(ang));
    const float2 Wbc = make_float2(Wb.x, -Wb.y);
    const float ci1r = c1r, ci1i = -c1i;

    const float* ip = in;
    float*       op = out;
    const float* sstdp = sstd;
    const float* rstdp = rstd;
    int bid = blockIdx.x;
    if (mean_i && bid == (int)gridDim.x - 1) {
        ip = mean_i; op = mean_o; sstdp = nullptr; rstdp = nullptr; bid = 0;
    }

    const int row0 = 2 * bid;
    const long long off0 = (long long)row0 * NN, off1 = off0 + NN;
    const int b   = row0 >> 12;
    const int rI0 = row0 & (NN - 1), rI1 = rI0 + 1;
    const float* sb = nullptr;
    float sI0 = 1.f, sI1 = 1.f;
    if (sstdp) { sb = sstdp + (long long)b * NN; sI0 = sb[rI0]; sI1 = sb[rI1]; }

    // batched loads: all global reads in flight before any LDS write
    float4 a4[4], c4[4], s4[4];
#pragma unroll
    for (int i = 0; i < 4; ++i) {
        int p = (tid + 256 * i) * 4;
        a4[i] = *(const float4*)(ip + off0 + p);
        c4[i] = *(const float4*)(ip + off1 + p);
    }
    if (sb) {
#pragma unroll
        for (int i = 0; i < 4; ++i) {
            int p = (tid + 256 * i) * 4;
            s4[i] = *(const float4*)(sb + p);
        }
    }
#pragma unroll
    for (int i = 0; i < 4; ++i) {
        int p = (tid + 256 * i) * 4;
        int r = p >> 6, c = p & 63;
        float4 a = a4[i], cc = c4[i];
        if (sb) {
            float4 s = s4[i];
            a.x *= sI0 * s.x; a.y *= sI0 * s.y; a.z *= sI0 * s.z; a.w *= sI0 * s.w;
            cc.x *= sI1 * s.x; cc.y *= sI1 * s.y; cc.z *= sI1 * s.z; cc.w *= sI1 * s.w;
        }
        float4* zp = (float4*)(z + r * CP + c);      // (r*CP+c) even -> aligned
        zp[0] = make_float4(a.x, cc.x, a.y, cc.y);
        zp[1] = make_float4(a.z, cc.z, a.w, cc.w);
    }
    __syncthreads();

    p1_fast_fwd(z, u, k1, c1r, c1i, s2, Wb);
    p2_slow_fwd(z, wfft_br, u, k1, c1r, c1i, s2, Wb);
    p3_slow_inv(z, u, k1, ci1r, ci1i, s2, Wbc);
    p4_fast_inv(z, u, k1, ci1r, ci1i, s2, Wbc);

    const float scale = 1.0f / 4096.0f;
    float s0 = scale, s1 = scale;
    const float* rsb = nullptr;
    if (rstdp) {
        rsb = rstdp + (long long)b * NN;
        s0 *= rsb[rI0];
        s1 *= rsb[rI1];
    }
#pragma unroll
    for (int i = 0; i < 4; ++i) {
        int p = (tid + 256 * i) * 4;
        int r = p >> 6, c = p & 63;
        const float4* zp = (const float4*)(z + r * CP + c);
        float4 v0 = zp[0], v1 = zp[1];
        float4 a  = make_float4(v0.x, v0.z, v1.x, v1.z);
        float4 cc = make_float4(v0.y, v0.w, v1.y, v1.w);
        if (rsb) {
            float4 rc = *(const float4*)(rsb + p);
            a.x *= s0 * rc.x; a.y *= s0 * rc.y; a.z *= s0 * rc.z; a.w *= s0 * rc.w;
            cc.x *= s1 * rc.x; cc.y *= s1 * rc.y; cc.z *= s1 * rc.z; cc.w *= s1 * rc.w;
        } else {
            a.x *= s0; a.y *= s0; a.z *= s0; a.w *= s0;
            cc.x *= s1; cc.y *= s1; cc.z *= s1; cc.w *= s1;
        }
        *(float4*)(op + off0 + p) = a;
        *(float4*)(op + off1 + p) = cc;
    }
}

// wfft in the transform layout via the SAME P1 + slow-fwd gather; the final
// spectrum is dumped straight from registers. Also zeroes the var accumulator.
__global__ __launch_bounds__(256, 2)
void wfft_kernel(const float* __restrict__ w, float2* wfft_br,
                 float* __restrict__ var_zero)
{
    __shared__ float2 z[64 * CP];
    const int tid = threadIdx.x;
#pragma unroll
    for (int i = 0; i < 32; ++i) var_zero[tid + 256 * i] = 0.f;
    const int u   = ((tid >> 6) << 4) | (tid & 15);
    const int k1  = (tid >> 4) & 3;
    const float c1r = (k1 == 0) ? 1.f : ((k1 == 2) ? -1.f : 0.f);
    const float c1i = (k1 == 1) ? -1.f : ((k1 == 3) ? 1.f : 0.f);
    const float s2  = (k1 & 1) ? -1.f : 1.f;
    const float ang = -0.09817477042468103f * (float)k1;
    const float2 Wb = make_float2(cosf(ang), sinf(ang));

#pragma unroll
    for (int i = 0; i < 16; ++i) {
        int p = tid + 256 * i;
        z[(p >> 6) * CP + (p & 63)] = make_float2(w[p], 0.f);
    }
    __syncthreads();
    p1_fast_fwd(z, u, k1, c1r, c1i, s2, Wb);
    float2 y[16];
    gather_cross4((const float4*)(z + u * CP), y, c1r, c1i, s2, Wb);
    fft16_fwd(y);
#pragma unroll
    for (int p = 0; p < 16; ++p)
        wfft_br[(16 * k1 + p) * 64 + u] = y[p];   // (slot)*64 + col convention
}

// In-place per-batch transpose of X1, TRIANGULAR grid, batched float4 I/O,
// FUSED diag (var) partials via 64-tap circular correlation w/ weight row.
__global__ __launch_bounds__(256, 4)
void transpose_inplace_kernel(float* data, const float* __restrict__ weight,
                              float* __restrict__ var)
{
    const int l = blockIdx.x;            // 0..2079 triangular index
    int bx = (int)((sqrtf(8.f * (float)l + 1.f) - 1.f) * 0.5f);
    while ((bx + 1) * (bx + 2) / 2 <= l) ++bx;   // fp guard
    while (bx * (bx + 1) / 2 > l) --bx;
    const int by = l - bx * (bx + 1) / 2;
    const int b  = blockIdx.y;

    __shared__ float tA[64 * 65];
    __shared__ float tB[64 * 65];
    __shared__ float wAs[64], wBs[64];
    __shared__ float red[512];
    const int tid = threadIdx.x;
    const int f  = tid & 15;
    const int r0 = tid >> 4;
    long long base = (long long)b * NN * NN;
    float* A  = data + base + (long long)(by * 64) * NN + bx * 64;
    float* Bt = data + base + (long long)(bx * 64) * NN + by * 64;

    if (tid < 64)       wAs[tid]      = weight[(((bx - by) & 63) << 6) + tid];
    else if (tid < 128) wBs[tid - 64] = weight[(((by - bx) & 63) << 6) + (tid - 64)];

    const int c = tid & 63, q = tid >> 6;

    if (bx == by) {
        float4 va[4];
#pragma unroll
        for (int it = 0; it < 4; ++it) {
            int r = r0 + 16 * it;
            va[it] = *(const float4*)(A + (long long)r * NN + 4 * f);
        }
#pragma unroll
        for (int it = 0; it < 4; ++it) {
            int r = r0 + 16 * it;
            tA[(4 * f + 0) * 65 + r] = va[it].x; tA[(4 * f + 1) * 65 + r] = va[it].y;
            tA[(4 * f + 2) * 65 + r] = va[it].z; tA[(4 * f + 3) * 65 + r] = va[it].w;
        }
        __syncthreads();
        float4 ov[4];
#pragma unroll
        for (int it = 0; it < 4; ++it) {
            int cc = r0 + 16 * it;
            ov[it].x = tA[cc * 65 + 4 * f + 0]; ov[it].y = tA[cc * 65 + 4 * f + 1];
            ov[it].z = tA[cc * 65 + 4 * f + 2]; ov[it].w = tA[cc * 65 + 4 * f + 3];
        }
        float sA = 0.f;
#pragma unroll
        for (int k = 0; k < 16; ++k) {
            int r = q * 16 + k;
            sA = fmaf(wAs[(c - r) & 63], tA[c * 65 + r], sA);
        }
        red[tid] = sA;
        __syncthreads();
        if (tid < 64) {
            float v = red[tid] + red[tid + 64] + red[tid + 128] + red[tid + 192];
            atomicAdd(&var[(long long)b * NN + bx * 64 + tid], v);
        }
#pragma unroll
        for (int it = 0; it < 4; ++it) {
            int cc = r0 + 16 * it;
            *(float4*)(A + (long long)cc * NN + 4 * f) = ov[it];
        }
    } else {
        float4 va[4], wb[4];
#pragma unroll
        for (int it = 0; it < 4; ++it) {
            int r = r0 + 16 * it;
            va[it] = *(const float4*)(A  + (long long)r * NN + 4 * f);
            wb[it] = *(const float4*)(Bt + (long long)r * NN + 4 * f);
        }
#pragma unroll
        for (int it = 0; it < 4; ++it) {
            int r = r0 + 16 * it;
            tA[(4 * f + 0) * 65 + r] = va[it].x; tA[(4 * f + 1) * 65 + r] = va[it].y;
            tA[(4 * f + 2) * 65 + r] = va[it].z; tA[(4 * f + 3) * 65 + r] = va[it].w;
            tB[(4 * f + 0) * 65 + r] = wb[it].x; tB[(4 * f + 1) * 65 + r] = wb[it].y;
            tB[(4 * f + 2) * 65 + r] = wb[it].z; tB[(4 * f + 3) * 65 + r] = wb[it].w;
        }
        __syncthreads();
        float4 ov[4], ow[4];
#pragma unroll
        for (int it = 0; it < 4; ++it) {
            int cc = r0 + 16 * it;
            ov[it].x = tB[cc * 65 + 4 * f + 0]; ov[it].y = tB[cc * 65 + 4 * f + 1];
            ov[it].z = tB[cc * 65 + 4 * f + 2]; ov[it].w = tB[cc * 65 + 4 * f + 3];
            ow[it].x = tA[cc * 65 + 4 * f + 0]; ow[it].y = tA[cc * 65 + 4 * f + 1];
            ow[it].z = tA[cc * 65 + 4 * f + 2]; ow[it].w = tA[cc * 65 + 4 * f + 3];
        }
        float sA = 0.f, sB = 0.f;
#pragma unroll
        for (int k = 0; k < 16; ++k) {
            int r = q * 16 + k;
            sA = fmaf(wAs[(c - r) & 63], tA[c * 65 + r], sA);
            sB = fmaf(wBs[(c - r) & 63], tB[c * 65 + r], sB);
        }
        red[tid] = sA; red[256 + tid] = sB;
        __syncthreads();
        if (tid < 64) {
            float v = red[tid] + red[tid + 64] + red[tid + 128] + red[tid + 192];
            atomicAdd(&var[(long long)b * NN + bx * 64 + tid], v);
        } else if (tid < 128) {
            int t = tid - 64;
            float v = red[256 + t] + red[320 + t] + red[384 + t] + red[448 + t];
            atomicAdd(&var[(long long)b * NN + by * 64 + t], v);
        }
#pragma unroll
        for (int it = 0; it < 4; ++it) {
            int cc = r0 + 16 * it;
            *(float4*)(A  + (long long)cc * NN + 4 * f) = ov[it];
            *(float4*)(Bt + (long long)cc * NN + 4 * f) = ow[it];
        }
    }
}

__global__ __launch_bounds__(256)
void std_kernel(const float* __restrict__ var, float* std_out, float* rstd, int n)
{
    int i = blockIdx.x * 256 + threadIdx.x;
    if (i < n) {
        float s = sqrtf(fmaxf(var[i], 1e-12f));
        std_out[i] = s;
        rstd[i] = 1.0f / s;
    }
}

extern "C" void kernel_launch(void* const* d_in, const int* in_sizes, int n_in,
                              void* d_out, int out_size, void* d_ws, size_t ws_size,
                              hipStream_t stream)
{
    const float* mean_in = (const float*)d_in[0];   // [2][64][64]
    const float* std_in  = (const float*)d_in[1];   // [2][64][64]
    const float* corr_in = (const float*)d_in[2];   // [2][4096][4096]
    const float* weight  = (const float*)d_in[3];   // [64][64]

    float* out      = (float*)d_out;
    float* mean_out = out;               // 8192
    float* std_out  = out + 8192;        // 8192
    float* corr_out = out + 16384;       // 2*4096*4096

    float*  ws      = (float*)d_ws;
    float2* wfft_br = (float2*)ws;       // 4096 float2 (8192 floats)
    float*  var_ws  = ws + 8192;         // 8192 floats
    float*  rstd_ws = ws + 16384;        // 8192 floats

    // D1: wfft + var-accumulator zeroing
    wfft_kernel<<<1, 256, 0, stream>>>(weight, wfft_br, var_ws);

    // D2 (K1): conv along K for every row pair (s[I]*s[K] scaling) -> X1.
    // Last block handles the mean path.
    row_conv2_kernel<<<NB * NN / 2 + 1, 256, 0, stream>>>(
        corr_in, corr_out, wfft_br, std_in, nullptr, mean_in, mean_out);

    // D3 (K2): in-place transpose -> X1^T, fused diag-of-cov, triangular grid
    transpose_inplace_kernel<<<dim3(2080, NB), 256, 0, stream>>>(corr_out, weight,
                                                                 var_ws);

    // D4: std/rstd from the diagonal
    std_kernel<<<(NB * NN + 255) / 256, 256, 0, stream>>>(var_ws, std_out,
                                                          rstd_ws, NB * NN);

    // D5 (K3): conv along I, in place, fused normalize via rstd_ws.
    // Symmetry: no final transpose.
    row_conv2_kernel<<<NB * NN / 2, 256, 0, stream>>>(
        corr_out, corr_out, wfft_br, nullptr, rstd_ws, nullptr, nullptr);
}